// Round 8
// baseline (311.073 us; speedup 1.0000x reference)
//
#include <hip/hip_runtime.h>
#include <hip/hip_bf16.h>

#define CIN 192
#define C3 576
#define HWPX 16384
#define NHEADS 4
#define DH 48

typedef unsigned short ushort_t;
typedef __attribute__((ext_vector_type(8))) short bf16x8;
typedef __attribute__((ext_vector_type(4))) float f32x4;

__device__ __forceinline__ float bf2f(unsigned short u) {
    return __uint_as_float(((unsigned int)u) << 16);
}
__device__ __forceinline__ unsigned short f2bf(float f) {
    unsigned int u = __float_as_uint(f);
    unsigned int r = (u >> 16) & 1u;
    u += 0x7fffu + r;
    return (unsigned short)(u >> 16);
}
__device__ __forceinline__ void up8(uint4 a, float* o) {
    o[0] = __uint_as_float(a.x << 16); o[1] = __uint_as_float(a.x & 0xffff0000u);
    o[2] = __uint_as_float(a.y << 16); o[3] = __uint_as_float(a.y & 0xffff0000u);
    o[4] = __uint_as_float(a.z << 16); o[5] = __uint_as_float(a.z & 0xffff0000u);
    o[6] = __uint_as_float(a.w << 16); o[7] = __uint_as_float(a.w & 0xffff0000u);
}

#define ASYNC_COPY16(gptr, lptr)                                                   \
    __builtin_amdgcn_global_load_lds(                                              \
        (__attribute__((address_space(1))) void*)(gptr),                           \
        (__attribute__((address_space(3))) void*)(lptr), 16, 0, 0)

// ---------------------------------------------------------------------------
// k_cvtw: qkv_w fp32 [576,192] -> bf16 row-major
// ---------------------------------------------------------------------------
__global__ __launch_bounds__(256) void k_cvtw(const float* __restrict__ w,
                                              ushort_t* __restrict__ wb) {
    int i = (blockIdx.x * 256 + threadIdx.x) * 4;
    float4 v = *(const float4*)(w + i);
    uint2 pk;
    pk.x = (unsigned)f2bf(v.x) | ((unsigned)f2bf(v.y) << 16);
    pk.y = (unsigned)f2bf(v.z) | ((unsigned)f2bf(v.w) << 16);
    *(uint2*)(wb + i) = pk;
}

// ---------------------------------------------------------------------------
// k_gemm: D[pix][o] = sum_k A[pix][k] * B[o][k]  (x fp32 planar -> pre bf16)
// BM=128 x BN=192, 512 thr / 8 waves (4x2), wave = 32pix x 96o (2x6 frags)
// ---------------------------------------------------------------------------
__global__ __launch_bounds__(512) void k_gemm(const float* __restrict__ A,
                                              const ushort_t* __restrict__ B,
                                              ushort_t* __restrict__ C) {
    __shared__ ushort_t sA[2][128 * 32];
    __shared__ ushort_t sB[2][192 * 32];
    const int t = threadIdx.x;
    const int lane = t & 63, wave = t >> 6;
    const int wrow = wave >> 1, wcol = wave & 1;
    const int pix0 = blockIdx.x * 128;
    const int o0 = blockIdx.y * 192;
    const int b = blockIdx.z;
    const ushort_t* Bb = B + (size_t)o0 * CIN;

    const int cc = t >> 4;  // channel-in-tile 0..31
    const int jj = t & 15;  // pixel-octet 0..15

    ushort_t av[8];
    auto loadA = [&](int kc) {
        const float* Ab = A + (size_t)b * CIN * HWPX +
                          (size_t)(kc + cc) * HWPX + pix0 + jj * 8;
        float4 a0 = *(const float4*)Ab;
        float4 a1 = *(const float4*)(Ab + 4);
        av[0] = f2bf(a0.x); av[1] = f2bf(a0.y);
        av[2] = f2bf(a0.z); av[3] = f2bf(a0.w);
        av[4] = f2bf(a1.x); av[5] = f2bf(a1.y);
        av[6] = f2bf(a1.z); av[7] = f2bf(a1.w);
    };
    auto writeA = [&](int buf) {
        ushort_t* s = sA[buf];
#pragma unroll
        for (int i = 0; i < 8; ++i) {
            int row = jj * 8 + i;
            int slot = ((cc >> 3) + (row >> 1) + (row >> 3)) & 3;
            s[row * 32 + slot * 8 + (cc & 7)] = av[i];
        }
    };
    auto stageB = [&](int buf, int kc) {
        {
            int row = t >> 2, slot = t & 3;
            int g = (slot + (row >> 1)) & 3;
            const ushort_t* gp = Bb + (size_t)row * CIN + kc + g * 8;
            ushort_t* lp = &sB[buf][(wave * 64) * 8];
            ASYNC_COPY16(gp, lp);
        }
        if (t < 256) {
            int e = 512 + t;
            int row = e >> 2, slot = e & 3;
            int g = (slot + (row >> 1)) & 3;
            const ushort_t* gp = Bb + (size_t)row * CIN + kc + g * 8;
            ushort_t* lp = &sB[buf][(512 + wave * 64) * 8];
            ASYNC_COPY16(gp, lp);
        }
    };

    f32x4 acc[2][6];
#pragma unroll
    for (int mi = 0; mi < 2; ++mi)
#pragma unroll
        for (int ni = 0; ni < 6; ++ni) acc[mi][ni] = (f32x4){0.f, 0.f, 0.f, 0.f};

    loadA(0);
    writeA(0);
    stageB(0, 0);
#pragma unroll
    for (int ks = 0; ks < 6; ++ks) {
        __syncthreads();
        const int buf = ks & 1;
        if (ks < 5) {
            loadA((ks + 1) * 32);
            stageB(buf ^ 1, (ks + 1) * 32);
        }
        const ushort_t* a_ = sA[buf];
        const ushort_t* b_ = sB[buf];
        const int c = lane >> 4;
        bf16x8 af[2], bfr[6];
#pragma unroll
        for (int mi = 0; mi < 2; ++mi) {
            int row = wrow * 32 + mi * 16 + (lane & 15);
            int slot = (c + (row >> 1) + (row >> 3)) & 3;
            af[mi] = *(const bf16x8*)&a_[row * 32 + slot * 8];
        }
#pragma unroll
        for (int ni = 0; ni < 6; ++ni) {
            int row = wcol * 96 + ni * 16 + (lane & 15);
            int slot = (c - (row >> 1)) & 3;
            bfr[ni] = *(const bf16x8*)&b_[row * 32 + slot * 8];
        }
#pragma unroll
        for (int mi = 0; mi < 2; ++mi)
#pragma unroll
            for (int ni = 0; ni < 6; ++ni)
                acc[mi][ni] = __builtin_amdgcn_mfma_f32_16x16x32_bf16(
                    af[mi], bfr[ni], acc[mi][ni], 0, 0, 0);
        if (ks < 5) writeA(buf ^ 1);
    }

    const int ocol = lane & 15;
    const int prow = (lane >> 4) * 4;
#pragma unroll
    for (int mi = 0; mi < 2; ++mi) {
        int pix = pix0 + wrow * 32 + mi * 16 + prow;
#pragma unroll
        for (int ni = 0; ni < 6; ++ni) {
            int o = o0 + wcol * 96 + ni * 16 + ocol;
            f32x4 v = acc[mi][ni];
            ushort_t* Cp = C + ((size_t)b * C3 + o) * HWPX + pix;
            uint2 pk;
            pk.x = (unsigned)f2bf(v[0]) | ((unsigned)f2bf(v[1]) << 16);
            pk.y = (unsigned)f2bf(v[2]) | ((unsigned)f2bf(v[3]) << 16);
            *(uint2*)Cp = pk;
        }
    }
}

// ---------------------------------------------------------------------------
// k_gramdw: fused {3x3 depthwise conv on q,k} + {gram partials} + {ssq partials}
// grid (chunk=8, h=4, b=8), 256 thr / 4 waves. Wave owns 4 image rows.
// ---------------------------------------------------------------------------
__global__ __launch_bounds__(256, 1) void k_gramdw(const ushort_t* __restrict__ pre,
                                                   const float* __restrict__ dww,
                                                   float* __restrict__ gpart,
                                                   float* __restrict__ normp) {
    __shared__ ushort_t sC[4][2][96 * 40];
    __shared__ float sG[4][DH][DH];
    const int chunk = blockIdx.x, h = blockIdx.y, b = blockIdx.z;
    const int t = threadIdx.x;
    const int lane = t & 63, wave = t >> 6;

    const ushort_t* plane[3];
    float wreg[3][9];
#pragma unroll
    for (int u = 0; u < 3; ++u) {
        int id = lane + 64 * u;
        int c96 = id >> 1;
        int gch = (c96 < DH) ? (h * DH + c96) : (CIN + h * DH + (c96 - DH));
        plane[u] = pre + ((size_t)b * C3 + gch) * HWPX;
#pragma unroll
        for (int k = 0; k < 9; ++k) wreg[u][k] = dww[gch * 9 + k];
    }

    float ssq[3] = {0.f, 0.f, 0.f};
    f32x4 acc[3][3];
#pragma unroll
    for (int i = 0; i < 3; ++i)
#pragma unroll
        for (int j = 0; j < 3; ++j) acc[i][j] = (f32x4){0.f, 0.f, 0.f, 0.f};

    uint4 r0[3][3], r1[3][3];
    ushort_t lf[3][3], rg[3][3];

    auto LOADS = [&](int s) {
        int Y = chunk * 16 + wave * 4 + (s >> 2);
#pragma unroll
        for (int u = 0; u < 3; ++u) {
            int id = lane + 64 * u;
            int xs = ((s & 3) << 5) + ((id & 1) << 4);
#pragma unroll
            for (int r = 0; r < 3; ++r) {
                int YY = Y - 1 + r;
                bool ok = ((unsigned)YY < 128u);
                const ushort_t* rp = plane[u] + YY * 128;
                if (ok) {
                    r0[u][r] = *(const uint4*)(rp + xs);
                    r1[u][r] = *(const uint4*)(rp + xs + 8);
                    lf[u][r] = (xs > 0) ? rp[xs - 1] : (ushort_t)0;
                    rg[u][r] = (xs + 16 < 128) ? rp[xs + 16] : (ushort_t)0;
                } else {
                    r0[u][r] = make_uint4(0, 0, 0, 0);
                    r1[u][r] = make_uint4(0, 0, 0, 0);
                    lf[u][r] = 0;
                    rg[u][r] = 0;
                }
            }
        }
    };
    auto CONVWRITE = [&](int buf) {
#pragma unroll
        for (int u = 0; u < 3; ++u) {
            int id = lane + 64 * u;
            float in[3][18];
#pragma unroll
            for (int r = 0; r < 3; ++r) {
                in[r][0] = bf2f(lf[u][r]);
                up8(r0[u][r], &in[r][1]);
                up8(r1[u][r], &in[r][9]);
                in[r][17] = bf2f(rg[u][r]);
            }
            unsigned pk[8];
#pragma unroll
            for (int j2 = 0; j2 < 8; ++j2) {
                float o0 = 0.f, o1 = 0.f;
#pragma unroll
                for (int ky = 0; ky < 3; ++ky) {
                    o0 = fmaf(wreg[u][ky * 3 + 0], in[ky][2 * j2 + 0], o0);
                    o0 = fmaf(wreg[u][ky * 3 + 1], in[ky][2 * j2 + 1], o0);
                    o0 = fmaf(wreg[u][ky * 3 + 2], in[ky][2 * j2 + 2], o0);
                    o1 = fmaf(wreg[u][ky * 3 + 0], in[ky][2 * j2 + 1], o1);
                    o1 = fmaf(wreg[u][ky * 3 + 1], in[ky][2 * j2 + 2], o1);
                    o1 = fmaf(wreg[u][ky * 3 + 2], in[ky][2 * j2 + 3], o1);
                }
                ssq[u] = fmaf(o0, o0, ssq[u]);
                ssq[u] = fmaf(o1, o1, ssq[u]);
                pk[j2] = (unsigned)f2bf(o0) | ((unsigned)f2bf(o1) << 16);
            }
            uint4* dst = (uint4*)&sC[wave][buf][(id >> 1) * 40 + ((id & 1) << 4)];
            dst[0] = make_uint4(pk[0], pk[1], pk[2], pk[3]);
            dst[1] = make_uint4(pk[4], pk[5], pk[6], pk[7]);
        }
    };

    LOADS(0);
    CONVWRITE(0);
    int buf = 0;
    for (int s = 0; s < 16; ++s) {
        if (s < 15) LOADS(s + 1);
        const ushort_t* base = &sC[wave][buf][0];
        bf16x8 af[3], bk[3];
#pragma unroll
        for (int i = 0; i < 3; ++i)
            af[i] = *(const bf16x8*)(base + (i * 16 + (lane & 15)) * 40 + (lane >> 4) * 8);
#pragma unroll
        for (int j = 0; j < 3; ++j)
            bk[j] = *(const bf16x8*)(base + (48 + j * 16 + (lane & 15)) * 40 + (lane >> 4) * 8);
#pragma unroll
        for (int i = 0; i < 3; ++i)
#pragma unroll
            for (int j = 0; j < 3; ++j)
                acc[i][j] = __builtin_amdgcn_mfma_f32_16x16x32_bf16(af[i], bk[j],
                                                                    acc[i][j], 0, 0, 0);
        if (s < 15) CONVWRITE(buf ^ 1);
        buf ^= 1;
    }

    const int crow = (lane >> 4) * 4;
    const int dcol = lane & 15;
#pragma unroll
    for (int i = 0; i < 3; ++i)
#pragma unroll
        for (int j = 0; j < 3; ++j)
#pragma unroll
            for (int r = 0; r < 4; ++r)
                sG[wave][i * 16 + crow + r][j * 16 + dcol] = acc[i][j][r];
    __syncthreads();
    const float* sGf = &sG[0][0][0];
    float* g = gpart + (((size_t)(b * NHEADS + h)) * 8 + chunk) * (DH * DH);
    for (int e = t; e < DH * DH; e += 256)
        g[e] = sGf[e] + sGf[DH * DH + e] + sGf[2 * DH * DH + e] + sGf[3 * DH * DH + e];

    float* np = normp + ((((size_t)(b * NHEADS + h)) * 8 + chunk) * 4 + wave) * 192;
#pragma unroll
    for (int u = 0; u < 3; ++u) np[lane + 64 * u] = ssq[u];
}

// ---------------------------------------------------------------------------
// k_attn: sum gram+norm partials -> normalize -> softmax -> att fp32
// ---------------------------------------------------------------------------
__global__ __launch_bounds__(256) void k_attn(const float* __restrict__ gpart,
                                              const float* __restrict__ normp,
                                              const float* __restrict__ temperature,
                                              float* __restrict__ att) {
    __shared__ float sA[DH][DH + 1];
    __shared__ float nrm[96];
    const int h = blockIdx.x, b = blockIdx.y;
    const int t = threadIdx.x;
    const size_t bh = b * NHEADS + h;
    if (t < 96) {
        float s = 0.f;
        for (int ck = 0; ck < 8; ++ck)
#pragma unroll
            for (int w = 0; w < 4; ++w) {
                const float* np = normp + ((bh * 8 + ck) * 4 + w) * 192 + t * 2;
                s += np[0] + np[1];
            }
        nrm[t] = fmaxf(sqrtf(s), 1e-12f);
    }
    __syncthreads();
    const float* base = gpart + (bh * 8) * (DH * DH);
    for (int e = t; e < DH * DH; e += 256) {
        float s = 0.f;
#pragma unroll
        for (int c8 = 0; c8 < 8; ++c8) s += base[(size_t)c8 * DH * DH + e];
        int c = e / DH, d = e % DH;
        sA[c][d] = s / (nrm[c] * nrm[48 + d]) * temperature[h];
    }
    __syncthreads();
    if (t < DH) {
        float m = -1e30f;
#pragma unroll
        for (int d = 0; d < DH; ++d) m = fmaxf(m, sA[t][d]);
        float s = 0.f;
        float row[DH];
#pragma unroll
        for (int d = 0; d < DH; ++d) {
            row[d] = expf(sA[t][d] - m);
            s += row[d];
        }
        float inv = 1.f / s;
#pragma unroll
        for (int d = 0; d < DH; ++d) sA[t][d] = row[d] * inv;
    }
    __syncthreads();
    float* ob = att + bh * DH * DH;
    for (int e = t; e < DH * DH; e += 256) ob[e] = sA[e / DH][e % DH];
}

// ---------------------------------------------------------------------------
// k_mw: Mw[b][o][192] = proj_w @ blockdiag(att), bf16 out. grid (6 otile, b)
// ---------------------------------------------------------------------------
__global__ __launch_bounds__(256) void k_mw(const float* __restrict__ att,
                                            const float* __restrict__ proj_w,
                                            ushort_t* __restrict__ Mw) {
    __shared__ float satt[NHEADS][DH][DH];
    __shared__ float sproj[32][CIN];
    const int o0 = blockIdx.x * 32, b = blockIdx.y;
    const int t = threadIdx.x;
    {
        const float4* src = (const float4*)(att + (size_t)b * NHEADS * DH * DH);
        float4* dst = (float4*)&satt[0][0][0];
        for (int e = t; e < NHEADS * DH * DH / 4; e += 256) dst[e] = src[e];
        const float4* ps = (const float4*)(proj_w + (size_t)o0 * CIN);
        float4* pd = (float4*)&sproj[0][0];
        for (int e = t; e < 32 * CIN / 4; e += 256) pd[e] = ps[e];
    }
    __syncthreads();
    ushort_t* ob = Mw + (size_t)b * CIN * CIN + (size_t)o0 * CIN;
    for (int e = t; e < 32 * CIN; e += 256) {
        int o = e / CIN, dg = e % CIN;
        int h = dg / DH, d = dg % DH;
        float s = 0.f;
#pragma unroll
        for (int c = 0; c < DH; ++c) s = fmaf(sproj[o][h * DH + c], satt[h][c][d], s);
        ob[e] = f2bf(s);
    }
}

// ---------------------------------------------------------------------------
// k_gemmv: out[o][pix] = sum_ch Mw[o][ch] * dw3x3(v)[ch][pix]
// dw conv fused into A-staging (reads raw pre v-planes + row halo).
// BM=128 (one image row), BN=192 (all o), 512 thr / 8 waves.
// ---------------------------------------------------------------------------
__global__ __launch_bounds__(512) void k_gemmv(const ushort_t* __restrict__ pre,
                                               const float* __restrict__ dww,
                                               const ushort_t* __restrict__ B,
                                               float* __restrict__ C) {
    __shared__ ushort_t sA[2][128 * 32];
    __shared__ ushort_t sB[2][192 * 32];
    const int t = threadIdx.x;
    const int lane = t & 63, wave = t >> 6;
    const int wrow = wave >> 1, wcol = wave & 1;
    const int Y = blockIdx.x;
    const int pix0 = Y * 128;
    const int b = blockIdx.z;
    const ushort_t* Bb = B + (size_t)b * CIN * CIN;

    const int cc = t >> 4;       // channel-in-tile 0..31
    const int jj = t & 15;       // pixel-octet 0..15
    const int x0 = jj * 8;

    uint4 m[3];
    ushort_t l16[3], rg16[3];
    float wv[9];
    ushort_t av[8];

    auto loadV = [&](int kc) {
        int ch = kc + cc;
        const ushort_t* pl = pre + ((size_t)b * C3 + 2 * CIN + ch) * HWPX;
#pragma unroll
        for (int r = 0; r < 3; ++r) {
            int YY = Y - 1 + r;
            bool ok = ((unsigned)YY < 128u);
            const ushort_t* rp = pl + YY * 128;
            if (ok) {
                m[r] = *(const uint4*)(rp + x0);
                l16[r] = (x0 > 0) ? rp[x0 - 1] : (ushort_t)0;
                rg16[r] = (x0 < 120) ? rp[x0 + 8] : (ushort_t)0;
            } else {
                m[r] = make_uint4(0, 0, 0, 0);
                l16[r] = 0;
                rg16[r] = 0;
            }
        }
#pragma unroll
        for (int k = 0; k < 9; ++k) wv[k] = dww[(2 * CIN + ch) * 9 + k];
    };
    auto convV = [&]() {
        float in[3][10];
#pragma unroll
        for (int r = 0; r < 3; ++r) {
            in[r][0] = bf2f(l16[r]);
            up8(m[r], &in[r][1]);
            in[r][9] = bf2f(rg16[r]);
        }
#pragma unroll
        for (int j = 0; j < 8; ++j) {
            float o = 0.f;
#pragma unroll
            for (int ky = 0; ky < 3; ++ky) {
                o = fmaf(wv[ky * 3 + 0], in[ky][j + 0], o);
                o = fmaf(wv[ky * 3 + 1], in[ky][j + 1], o);
                o = fmaf(wv[ky * 3 + 2], in[ky][j + 2], o);
            }
            av[j] = f2bf(o);
        }
    };
    auto writeA = [&](int buf) {
        ushort_t* s = sA[buf];
#pragma unroll
        for (int i = 0; i < 8; ++i) {
            int row = jj * 8 + i;
            int slot = ((cc >> 3) + (row >> 1) + (row >> 3)) & 3;
            s[row * 32 + slot * 8 + (cc & 7)] = av[i];
        }
    };
    auto stageB = [&](int buf, int kc) {
        {
            int row = t >> 2, slot = t & 3;
            int g = (slot + (row >> 1)) & 3;
            const ushort_t* gp = Bb + (size_t)row * CIN + kc + g * 8;
            ushort_t* lp = &sB[buf][(wave * 64) * 8];
            ASYNC_COPY16(gp, lp);
        }
        if (t < 256) {
            int e = 512 + t;
            int row = e >> 2, slot = e & 3;
            int g = (slot + (row >> 1)) & 3;
            const ushort_t* gp = Bb + (size_t)row * CIN + kc + g * 8;
            ushort_t* lp = &sB[buf][(512 + wave * 64) * 8];
            ASYNC_COPY16(gp, lp);
        }
    };

    f32x4 acc[2][6];
#pragma unroll
    for (int mi = 0; mi < 2; ++mi)
#pragma unroll
        for (int ni = 0; ni < 6; ++ni) acc[mi][ni] = (f32x4){0.f, 0.f, 0.f, 0.f};

    loadV(0);
    convV();
    writeA(0);
    stageB(0, 0);
#pragma unroll
    for (int ks = 0; ks < 6; ++ks) {
        __syncthreads();
        const int buf = ks & 1;
        if (ks < 5) {
            loadV((ks + 1) * 32);
            stageB(buf ^ 1, (ks + 1) * 32);
        }
        const ushort_t* a_ = sA[buf];
        const ushort_t* b_ = sB[buf];
        const int c = lane >> 4;
        bf16x8 af[2], bfr[6];
#pragma unroll
        for (int mi = 0; mi < 2; ++mi) {
            int row = wrow * 32 + mi * 16 + (lane & 15);
            int slot = (c + (row >> 1) + (row >> 3)) & 3;
            af[mi] = *(const bf16x8*)&a_[row * 32 + slot * 8];
        }
#pragma unroll
        for (int ni = 0; ni < 6; ++ni) {
            int row = wcol * 96 + ni * 16 + (lane & 15);
            int slot = (c - (row >> 1)) & 3;
            bfr[ni] = *(const bf16x8*)&b_[row * 32 + slot * 8];
        }
#pragma unroll
        for (int mi = 0; mi < 2; ++mi)
#pragma unroll
            for (int ni = 0; ni < 6; ++ni)
                acc[mi][ni] = __builtin_amdgcn_mfma_f32_16x16x32_bf16(
                    af[mi], bfr[ni], acc[mi][ni], 0, 0, 0);
        if (ks < 5) {
            convV();
            writeA(buf ^ 1);
        }
    }

    const int ocol = lane & 15;
    const int prow = (lane >> 4) * 4;
#pragma unroll
    for (int mi = 0; mi < 2; ++mi) {
        int pix = pix0 + wrow * 32 + mi * 16 + prow;
#pragma unroll
        for (int ni = 0; ni < 6; ++ni) {
            int o = wcol * 96 + ni * 16 + ocol;
            f32x4 v = acc[mi][ni];
            float* Cp = C + ((size_t)b * CIN + o) * HWPX + pix;
            *(float4*)Cp = make_float4(v[0], v[1], v[2], v[3]);
        }
    }
}

extern "C" void kernel_launch(void* const* d_in, const int* in_sizes, int n_in,
                              void* d_out, int out_size, void* d_ws, size_t ws_size,
                              hipStream_t stream) {
    const float* x = (const float*)d_in[0];
    const float* qkv_w = (const float*)d_in[1];
    const float* dw_w = (const float*)d_in[2];
    const float* proj_w = (const float*)d_in[3];
    const float* temperature = (const float*)d_in[4];
    float* out = (float*)d_out;

    char* ws = (char*)d_ws;
    // layout (bytes), total ~155.3 MB:
    //   [0, 150994944)            pre   bf16 [b][576][16384]
    //   [150994944, +786432)      normp fp32 [bh][8][4][192]
    //   [151781376, +2359296)     gpart fp32
    //   [154140672, +589824)      Mw    bf16
    //   [154730496, +294912)      attb  fp32
    //   [155025408, +221184)      wq    bf16
    ushort_t* pre = (ushort_t*)ws;
    float* normp = (float*)(ws + 150994944);
    float* gpart = (float*)(ws + 151781376);
    ushort_t* Mw = (ushort_t*)(ws + 154140672);
    float* attb = (float*)(ws + 154730496);
    ushort_t* wq = (ushort_t*)(ws + 155025408);

    k_cvtw<<<dim3(108), 256, 0, stream>>>(qkv_w, wq);
    k_gemm<<<dim3(128, 3, 8), 512, 0, stream>>>(x, wq, pre);
    k_gramdw<<<dim3(8, NHEADS, 8), 256, 0, stream>>>(pre, dw_w, gpart, normp);
    k_attn<<<dim3(NHEADS, 8), 256, 0, stream>>>(gpart, normp, temperature, attb);
    k_mw<<<dim3(6, 8), 256, 0, stream>>>(attb, proj_w, Mw);
    k_gemmv<<<dim3(128, 1, 8), 512, 0, stream>>>(pre, dw_w, Mw, out);
}

// Round 9
// 241.980 us; speedup vs baseline: 1.2855x; 1.2855x over previous
//
#include <hip/hip_runtime.h>
#include <hip/hip_bf16.h>

#define CIN 192
#define C3 576
#define HWPX 16384
#define NHEADS 4
#define DH 48

typedef unsigned short ushort_t;
typedef __attribute__((ext_vector_type(8))) short bf16x8;
typedef __attribute__((ext_vector_type(4))) float f32x4;

__device__ __forceinline__ float bf2f(unsigned short u) {
    return __uint_as_float(((unsigned int)u) << 16);
}
__device__ __forceinline__ unsigned short f2bf(float f) {
    unsigned int u = __float_as_uint(f);
    unsigned int r = (u >> 16) & 1u;
    u += 0x7fffu + r;
    return (unsigned short)(u >> 16);
}
__device__ __forceinline__ void up8(uint4 a, float* o) {
    o[0] = __uint_as_float(a.x << 16); o[1] = __uint_as_float(a.x & 0xffff0000u);
    o[2] = __uint_as_float(a.y << 16); o[3] = __uint_as_float(a.y & 0xffff0000u);
    o[4] = __uint_as_float(a.z << 16); o[5] = __uint_as_float(a.z & 0xffff0000u);
    o[6] = __uint_as_float(a.w << 16); o[7] = __uint_as_float(a.w & 0xffff0000u);
}

#define ASYNC_COPY16(gptr, lptr)                                                   \
    __builtin_amdgcn_global_load_lds(                                              \
        (__attribute__((address_space(1))) void*)(gptr),                           \
        (__attribute__((address_space(3))) void*)(lptr), 16, 0, 0)

// ---------------------------------------------------------------------------
// k_cvtw: qkv_w fp32 [576,192] -> bf16 row-major
// ---------------------------------------------------------------------------
__global__ __launch_bounds__(256) void k_cvtw(const float* __restrict__ w,
                                              ushort_t* __restrict__ wb) {
    int i = (blockIdx.x * 256 + threadIdx.x) * 4;
    float4 v = *(const float4*)(w + i);
    uint2 pk;
    pk.x = (unsigned)f2bf(v.x) | ((unsigned)f2bf(v.y) << 16);
    pk.y = (unsigned)f2bf(v.z) | ((unsigned)f2bf(v.w) << 16);
    *(uint2*)(wb + i) = pk;
}

// ---------------------------------------------------------------------------
// k_gemm: pre[o][pix] = sum_k x[k][pix] * wq[o][k]   (MFMA bf16)
// BM=128 pix x BN=288 o (2 o-passes), 512 thr / 8 waves (4x2),
// wave = 32pix x 144o (2x9 frags)
// ---------------------------------------------------------------------------
__global__ __launch_bounds__(512) void k_gemm(const float* __restrict__ A,
                                              const ushort_t* __restrict__ B,
                                              ushort_t* __restrict__ C) {
    __shared__ ushort_t sA[2][128 * 32];
    __shared__ ushort_t sB[2][288 * 32];
    const int t = threadIdx.x;
    const int lane = t & 63, wave = t >> 6;
    const int wrow = wave >> 1, wcol = wave & 1;
    const int pix0 = blockIdx.x * 128;
    const int o0 = blockIdx.y * 288;
    const int b = blockIdx.z;
    const ushort_t* Bb = B + (size_t)o0 * CIN;

    const int cc = t >> 4;  // channel-in-tile 0..31
    const int jj = t & 15;  // pixel-octet 0..15

    ushort_t av[8];
    auto loadA = [&](int kc) {
        const float* Ab = A + (size_t)b * CIN * HWPX +
                          (size_t)(kc + cc) * HWPX + pix0 + jj * 8;
        float4 a0 = *(const float4*)Ab;
        float4 a1 = *(const float4*)(Ab + 4);
        av[0] = f2bf(a0.x); av[1] = f2bf(a0.y);
        av[2] = f2bf(a0.z); av[3] = f2bf(a0.w);
        av[4] = f2bf(a1.x); av[5] = f2bf(a1.y);
        av[6] = f2bf(a1.z); av[7] = f2bf(a1.w);
    };
    auto writeA = [&](int buf) {
        ushort_t* s = sA[buf];
#pragma unroll
        for (int i = 0; i < 8; ++i) {
            int row = jj * 8 + i;
            int slot = ((cc >> 3) + (row >> 1) + (row >> 3)) & 3;
            s[row * 32 + slot * 8 + (cc & 7)] = av[i];
        }
    };
    auto stageB = [&](int buf, int kc) {
#pragma unroll
        for (int c = 0; c < 2; ++c) {
            int e = c * 512 + t;
            int row = e >> 2, slot = e & 3;
            int g = (slot + (row >> 1)) & 3;
            const ushort_t* gp = Bb + (size_t)row * CIN + kc + g * 8;
            ushort_t* lp = &sB[buf][(c * 512 + wave * 64) * 8];
            ASYNC_COPY16(gp, lp);
        }
        if (t < 128) {
            int e = 1024 + t;
            int row = e >> 2, slot = e & 3;
            int g = (slot + (row >> 1)) & 3;
            const ushort_t* gp = Bb + (size_t)row * CIN + kc + g * 8;
            ushort_t* lp = &sB[buf][(1024 + wave * 64) * 8];
            ASYNC_COPY16(gp, lp);
        }
    };

    f32x4 acc[2][9];
#pragma unroll
    for (int mi = 0; mi < 2; ++mi)
#pragma unroll
        for (int ni = 0; ni < 9; ++ni) acc[mi][ni] = (f32x4){0.f, 0.f, 0.f, 0.f};

    loadA(0);
    writeA(0);
    stageB(0, 0);
#pragma unroll
    for (int ks = 0; ks < 6; ++ks) {
        __syncthreads();
        const int buf = ks & 1;
        if (ks < 5) {
            loadA((ks + 1) * 32);
            stageB(buf ^ 1, (ks + 1) * 32);
        }
        const ushort_t* a_ = sA[buf];
        const ushort_t* b_ = sB[buf];
        const int c = lane >> 4;
        bf16x8 af[2], bfr[9];
#pragma unroll
        for (int mi = 0; mi < 2; ++mi) {
            int row = wrow * 32 + mi * 16 + (lane & 15);
            int slot = (c + (row >> 1) + (row >> 3)) & 3;
            af[mi] = *(const bf16x8*)&a_[row * 32 + slot * 8];
        }
#pragma unroll
        for (int ni = 0; ni < 9; ++ni) {
            int row = wcol * 144 + ni * 16 + (lane & 15);
            int slot = (c - (row >> 1)) & 3;
            bfr[ni] = *(const bf16x8*)&b_[row * 32 + slot * 8];
        }
#pragma unroll
        for (int mi = 0; mi < 2; ++mi)
#pragma unroll
            for (int ni = 0; ni < 9; ++ni)
                acc[mi][ni] = __builtin_amdgcn_mfma_f32_16x16x32_bf16(
                    af[mi], bfr[ni], acc[mi][ni], 0, 0, 0);
        if (ks < 5) writeA(buf ^ 1);
    }

    const int ocol = lane & 15;
    const int prow = (lane >> 4) * 4;
#pragma unroll
    for (int mi = 0; mi < 2; ++mi) {
        int pix = pix0 + wrow * 32 + mi * 16 + prow;
#pragma unroll
        for (int ni = 0; ni < 9; ++ni) {
            int o = o0 + wcol * 144 + ni * 16 + ocol;
            f32x4 v = acc[mi][ni];
            ushort_t* Cp = C + ((size_t)b * C3 + o) * HWPX + pix;
            uint2 pk;
            pk.x = (unsigned)f2bf(v[0]) | ((unsigned)f2bf(v[1]) << 16);
            pk.y = (unsigned)f2bf(v[2]) | ((unsigned)f2bf(v[3]) << 16);
            *(uint2*)Cp = pk;
        }
    }
}

// ---------------------------------------------------------------------------
// k_gramdw: fused {3x3 dw conv on q,k} + {gram partials} + {ssq partials}
// grid (chunk=8, h=4, b=8), 256 thr / 4 waves. Wave = 32-px column strip,
// y slides chunk*16 .. +15; per step load ONLY the new row (ring of 3 in regs,
// 1-row prefetch). Per-wave single-buffer LDS tile (no cross-wave hazard).
// Unit u: id = lane+64u (0..191): ch96 = id>>1, half = id&1 (16 px each).
// ---------------------------------------------------------------------------
__global__ __launch_bounds__(256, 1) void k_gramdw(const ushort_t* __restrict__ pre,
                                                   const float* __restrict__ dww,
                                                   float* __restrict__ gpart,
                                                   float* __restrict__ normp) {
    __shared__ char smem[NHEADS * DH * DH * 4];  // 36864 B: sC (30720) / sG union
    ushort_t* sCw = (ushort_t*)smem + (threadIdx.x >> 6) * (96 * 40);
    float* sG = (float*)smem;

    const int chunk = blockIdx.x, h = blockIdx.y, b = blockIdx.z;
    const int t = threadIdx.x;
    const int lane = t & 63, wave = t >> 6;
    const int y0 = chunk * 16;

    const ushort_t* plane[3];
    float wreg[3][9];
    int pxb[3];
#pragma unroll
    for (int u = 0; u < 3; ++u) {
        int id = lane + 64 * u;
        int c96 = id >> 1;
        int gch = (c96 < DH) ? (h * DH + c96) : (CIN + h * DH + (c96 - DH));
        plane[u] = pre + ((size_t)b * C3 + gch) * HWPX;
        pxb[u] = wave * 32 + (id & 1) * 16;
#pragma unroll
        for (int k = 0; k < 9; ++k) wreg[u][k] = dww[gch * 9 + k];
    }

    float ssq[3] = {0.f, 0.f, 0.f};
    f32x4 acc[3][3];
#pragma unroll
    for (int i = 0; i < 3; ++i)
#pragma unroll
        for (int j = 0; j < 3; ++j) acc[i][j] = (f32x4){0.f, 0.f, 0.f, 0.f};

    uint4 ring[3][3][2];        // [rowpos][unit][octet]
    ushort_t lfr[3][3], rgr[3][3];
    uint4 nx[3][2];
    ushort_t nlf[3], nrg[3];

    auto LOADROW = [&](int YY) {
#pragma unroll
        for (int u = 0; u < 3; ++u) {
            bool ok = ((unsigned)YY < 128u);
            const ushort_t* rp = plane[u] + YY * 128 + pxb[u];
            if (ok) {
                nx[u][0] = *(const uint4*)rp;
                nx[u][1] = *(const uint4*)(rp + 8);
                nlf[u] = (pxb[u] > 0) ? rp[-1] : (ushort_t)0;
                nrg[u] = (pxb[u] + 16 < 128) ? rp[16] : (ushort_t)0;
            } else {
                nx[u][0] = make_uint4(0, 0, 0, 0);
                nx[u][1] = make_uint4(0, 0, 0, 0);
                nlf[u] = 0;
                nrg[u] = 0;
            }
        }
    };
    auto PUT = [&](int rp) {
#pragma unroll
        for (int u = 0; u < 3; ++u) {
            ring[rp][u][0] = nx[u][0];
            ring[rp][u][1] = nx[u][1];
            lfr[rp][u] = nlf[u];
            rgr[rp][u] = nrg[u];
        }
    };

    LOADROW(y0 - 1); PUT(0);
    LOADROW(y0);     PUT(1);
    LOADROW(y0 + 1); PUT(2);

    for (int s = 0; s < 16; ++s) {
        if (s < 15) LOADROW(y0 + s + 2);  // prefetch, lands in nx
        // conv row y0+s for all 3 units, write LDS tile
#pragma unroll
        for (int u = 0; u < 3; ++u) {
            int id = lane + 64 * u;
            float in[3][18];
#pragma unroll
            for (int r = 0; r < 3; ++r) {
                in[r][0] = bf2f(lfr[r][u]);
                up8(ring[r][u][0], &in[r][1]);
                up8(ring[r][u][1], &in[r][9]);
                in[r][17] = bf2f(rgr[r][u]);
            }
            unsigned pk[8];
#pragma unroll
            for (int j2 = 0; j2 < 8; ++j2) {
                float o0 = 0.f, o1 = 0.f;
#pragma unroll
                for (int ky = 0; ky < 3; ++ky) {
                    o0 = fmaf(wreg[u][ky * 3 + 0], in[ky][2 * j2 + 0], o0);
                    o0 = fmaf(wreg[u][ky * 3 + 1], in[ky][2 * j2 + 1], o0);
                    o0 = fmaf(wreg[u][ky * 3 + 2], in[ky][2 * j2 + 2], o0);
                    o1 = fmaf(wreg[u][ky * 3 + 0], in[ky][2 * j2 + 1], o1);
                    o1 = fmaf(wreg[u][ky * 3 + 1], in[ky][2 * j2 + 2], o1);
                    o1 = fmaf(wreg[u][ky * 3 + 2], in[ky][2 * j2 + 3], o1);
                }
                ssq[u] = fmaf(o0, o0, ssq[u]);
                ssq[u] = fmaf(o1, o1, ssq[u]);
                pk[j2] = (unsigned)f2bf(o0) | ((unsigned)f2bf(o1) << 16);
            }
            uint4* dst = (uint4*)&sCw[(id >> 1) * 40 + ((id & 1) << 4)];
            dst[0] = make_uint4(pk[0], pk[1], pk[2], pk[3]);
            dst[1] = make_uint4(pk[4], pk[5], pk[6], pk[7]);
        }
        // MFMA on this wave's tile (ds ordering within wave; no barrier needed)
        {
            bf16x8 af[3], bk[3];
#pragma unroll
            for (int i = 0; i < 3; ++i)
                af[i] = *(const bf16x8*)&sCw[(i * 16 + (lane & 15)) * 40 + (lane >> 4) * 8];
#pragma unroll
            for (int j = 0; j < 3; ++j)
                bk[j] = *(const bf16x8*)&sCw[(48 + j * 16 + (lane & 15)) * 40 + (lane >> 4) * 8];
#pragma unroll
            for (int i = 0; i < 3; ++i)
#pragma unroll
                for (int j = 0; j < 3; ++j)
                    acc[i][j] = __builtin_amdgcn_mfma_f32_16x16x32_bf16(af[i], bk[j],
                                                                        acc[i][j], 0, 0, 0);
        }
        if (s < 15) {
            // slide ring down one row
#pragma unroll
            for (int u = 0; u < 3; ++u) {
                ring[0][u][0] = ring[1][u][0]; ring[0][u][1] = ring[1][u][1];
                ring[1][u][0] = ring[2][u][0]; ring[1][u][1] = ring[2][u][1];
                ring[2][u][0] = nx[u][0];      ring[2][u][1] = nx[u][1];
                lfr[0][u] = lfr[1][u]; lfr[1][u] = lfr[2][u]; lfr[2][u] = nlf[u];
                rgr[0][u] = rgr[1][u]; rgr[1][u] = rgr[2][u]; rgr[2][u] = nrg[u];
            }
        }
    }

    __syncthreads();  // sC dead for ALL waves before sG overlay writes
    const int crow = (lane >> 4) * 4;
    const int dcol = lane & 15;
#pragma unroll
    for (int i = 0; i < 3; ++i)
#pragma unroll
        for (int j = 0; j < 3; ++j)
#pragma unroll
            for (int r = 0; r < 4; ++r)
                sG[(size_t)wave * DH * DH + (i * 16 + crow + r) * DH + j * 16 + dcol] =
                    acc[i][j][r];
    __syncthreads();
    float* g = gpart + (((size_t)(b * NHEADS + h)) * 8 + chunk) * (DH * DH);
    for (int e = t; e < DH * DH; e += 256)
        g[e] = sG[e] + sG[DH * DH + e] + sG[2 * DH * DH + e] + sG[3 * DH * DH + e];

    float* np = normp + ((((size_t)(b * NHEADS + h)) * 8 + chunk) * 4 + wave) * 192;
#pragma unroll
    for (int u = 0; u < 3; ++u) np[lane + 64 * u] = ssq[u];
}

// ---------------------------------------------------------------------------
// k_attn: sum gram+norm partials -> normalize -> softmax -> att fp32
// ---------------------------------------------------------------------------
__global__ __launch_bounds__(256) void k_attn(const float* __restrict__ gpart,
                                              const float* __restrict__ normp,
                                              const float* __restrict__ temperature,
                                              float* __restrict__ att) {
    __shared__ float sA[DH][DH + 1];
    __shared__ float nrm[96];
    const int h = blockIdx.x, b = blockIdx.y;
    const int t = threadIdx.x;
    const size_t bh = b * NHEADS + h;
    if (t < 96) {
        float s = 0.f;
        for (int ck = 0; ck < 8; ++ck)
#pragma unroll
            for (int w = 0; w < 4; ++w) {
                const float* np = normp + ((bh * 8 + ck) * 4 + w) * 192 + t * 2;
                s += np[0] + np[1];
            }
        nrm[t] = fmaxf(sqrtf(s), 1e-12f);
    }
    __syncthreads();
    const float* base = gpart + (bh * 8) * (DH * DH);
    for (int e = t; e < DH * DH; e += 256) {
        float s = 0.f;
#pragma unroll
        for (int c8 = 0; c8 < 8; ++c8) s += base[(size_t)c8 * DH * DH + e];
        int c = e / DH, d = e % DH;
        sA[c][d] = s / (nrm[c] * nrm[48 + d]) * temperature[h];
    }
    __syncthreads();
    if (t < DH) {
        float m = -1e30f;
#pragma unroll
        for (int d = 0; d < DH; ++d) m = fmaxf(m, sA[t][d]);
        float s = 0.f;
        float row[DH];
#pragma unroll
        for (int d = 0; d < DH; ++d) {
            row[d] = expf(sA[t][d] - m);
            s += row[d];
        }
        float inv = 1.f / s;
#pragma unroll
        for (int d = 0; d < DH; ++d) sA[t][d] = row[d] * inv;
    }
    __syncthreads();
    float* ob = att + bh * DH * DH;
    for (int e = t; e < DH * DH; e += 256) ob[e] = sA[e / DH][e % DH];
}

// ---------------------------------------------------------------------------
// k_mw: Mw[b][o][192] = proj_w @ blockdiag(att), bf16 out. grid (6 otile, b)
// ---------------------------------------------------------------------------
__global__ __launch_bounds__(256) void k_mw(const float* __restrict__ att,
                                            const float* __restrict__ proj_w,
                                            ushort_t* __restrict__ Mw) {
    __shared__ float satt[NHEADS][DH][DH];
    __shared__ float sproj[32][CIN];
    const int o0 = blockIdx.x * 32, b = blockIdx.y;
    const int t = threadIdx.x;
    {
        const float4* src = (const float4*)(att + (size_t)b * NHEADS * DH * DH);
        float4* dst = (float4*)&satt[0][0][0];
        for (int e = t; e < NHEADS * DH * DH / 4; e += 256) dst[e] = src[e];
        const float4* ps = (const float4*)(proj_w + (size_t)o0 * CIN);
        float4* pd = (float4*)&sproj[0][0];
        for (int e = t; e < 32 * CIN / 4; e += 256) pd[e] = ps[e];
    }
    __syncthreads();
    ushort_t* ob = Mw + (size_t)b * CIN * CIN + (size_t)o0 * CIN;
    for (int e = t; e < 32 * CIN; e += 256) {
        int o = e / CIN, dg = e % CIN;
        int h = dg / DH, d = dg % DH;
        float s = 0.f;
#pragma unroll
        for (int c = 0; c < DH; ++c) s = fmaf(sproj[o][h * DH + c], satt[h][c][d], s);
        ob[e] = f2bf(s);
    }
}

// ---------------------------------------------------------------------------
// k_gemmv: out[o][pix] = sum_ch Mw[o][ch] * dw3x3(v)[ch][pix]
// dw conv fused into A-staging (reads raw pre v-planes + row halo).
// BM=128 (one image row), BN=192 (all o), 512 thr / 8 waves.
// ---------------------------------------------------------------------------
__global__ __launch_bounds__(512) void k_gemmv(const ushort_t* __restrict__ pre,
                                               const float* __restrict__ dww,
                                               const ushort_t* __restrict__ B,
                                               float* __restrict__ C) {
    __shared__ ushort_t sA[2][128 * 32];
    __shared__ ushort_t sB[2][192 * 32];
    const int t = threadIdx.x;
    const int lane = t & 63, wave = t >> 6;
    const int wrow = wave >> 1, wcol = wave & 1;
    const int Y = blockIdx.x;
    const int pix0 = Y * 128;
    const int b = blockIdx.z;
    const ushort_t* Bb = B + (size_t)b * CIN * CIN;

    const int cc = t >> 4;       // channel-in-tile 0..31
    const int jj = t & 15;       // pixel-octet 0..15
    const int x0 = jj * 8;

    uint4 m[3];
    ushort_t l16[3], rg16[3];
    float wv[9];
    ushort_t av[8];

    auto loadV = [&](int kc) {
        int ch = kc + cc;
        const ushort_t* pl = pre + ((size_t)b * C3 + 2 * CIN + ch) * HWPX;
#pragma unroll
        for (int r = 0; r < 3; ++r) {
            int YY = Y - 1 + r;
            bool ok = ((unsigned)YY < 128u);
            const ushort_t* rp = pl + YY * 128;
            if (ok) {
                m[r] = *(const uint4*)(rp + x0);
                l16[r] = (x0 > 0) ? rp[x0 - 1] : (ushort_t)0;
                rg16[r] = (x0 < 120) ? rp[x0 + 8] : (ushort_t)0;
            } else {
                m[r] = make_uint4(0, 0, 0, 0);
                l16[r] = 0;
                rg16[r] = 0;
            }
        }
#pragma unroll
        for (int k = 0; k < 9; ++k) wv[k] = dww[(2 * CIN + ch) * 9 + k];
    };
    auto convV = [&]() {
        float in[3][10];
#pragma unroll
        for (int r = 0; r < 3; ++r) {
            in[r][0] = bf2f(l16[r]);
            up8(m[r], &in[r][1]);
            in[r][9] = bf2f(rg16[r]);
        }
#pragma unroll
        for (int j = 0; j < 8; ++j) {
            float o = 0.f;
#pragma unroll
            for (int ky = 0; ky < 3; ++ky) {
                o = fmaf(wv[ky * 3 + 0], in[ky][j + 0], o);
                o = fmaf(wv[ky * 3 + 1], in[ky][j + 1], o);
                o = fmaf(wv[ky * 3 + 2], in[ky][j + 2], o);
            }
            av[j] = f2bf(o);
        }
    };
    auto writeA = [&](int buf) {
        ushort_t* s = sA[buf];
#pragma unroll
        for (int i = 0; i < 8; ++i) {
            int row = jj * 8 + i;
            int slot = ((cc >> 3) + (row >> 1) + (row >> 3)) & 3;
            s[row * 32 + slot * 8 + (cc & 7)] = av[i];
        }
    };
    auto stageB = [&](int buf, int kc) {
        {
            int row = t >> 2, slot = t & 3;
            int g = (slot + (row >> 1)) & 3;
            const ushort_t* gp = Bb + (size_t)row * CIN + kc + g * 8;
            ushort_t* lp = &sB[buf][(wave * 64) * 8];
            ASYNC_COPY16(gp, lp);
        }
        if (t < 256) {
            int e = 512 + t;
            int row = e >> 2, slot = e & 3;
            int g = (slot + (row >> 1)) & 3;
            const ushort_t* gp = Bb + (size_t)row * CIN + kc + g * 8;
            ushort_t* lp = &sB[buf][(512 + wave * 64) * 8];
            ASYNC_COPY16(gp, lp);
        }
    };

    f32x4 acc[2][6];
#pragma unroll
    for (int mi = 0; mi < 2; ++mi)
#pragma unroll
        for (int ni = 0; ni < 6; ++ni) acc[mi][ni] = (f32x4){0.f, 0.f, 0.f, 0.f};

    loadV(0);
    convV();
    writeA(0);
    stageB(0, 0);
#pragma unroll
    for (int ks = 0; ks < 6; ++ks) {
        __syncthreads();
        const int buf = ks & 1;
        if (ks < 5) {
            loadV((ks + 1) * 32);
            stageB(buf ^ 1, (ks + 1) * 32);
        }
        const ushort_t* a_ = sA[buf];
        const ushort_t* b_ = sB[buf];
        const int c = lane >> 4;
        bf16x8 af[2], bfr[6];
#pragma unroll
        for (int mi = 0; mi < 2; ++mi) {
            int row = wrow * 32 + mi * 16 + (lane & 15);
            int slot = (c + (row >> 1) + (row >> 3)) & 3;
            af[mi] = *(const bf16x8*)&a_[row * 32 + slot * 8];
        }
#pragma unroll
        for (int ni = 0; ni < 6; ++ni) {
            int row = wcol * 96 + ni * 16 + (lane & 15);
            int slot = (c - (row >> 1)) & 3;
            bfr[ni] = *(const bf16x8*)&b_[row * 32 + slot * 8];
        }
#pragma unroll
        for (int mi = 0; mi < 2; ++mi)
#pragma unroll
            for (int ni = 0; ni < 6; ++ni)
                acc[mi][ni] = __builtin_amdgcn_mfma_f32_16x16x32_bf16(
                    af[mi], bfr[ni], acc[mi][ni], 0, 0, 0);
        if (ks < 5) {
            convV();
            writeA(buf ^ 1);
        }
    }

    const int ocol = lane & 15;
    const int prow = (lane >> 4) * 4;
#pragma unroll
    for (int mi = 0; mi < 2; ++mi) {
        int pix = pix0 + wrow * 32 + mi * 16 + prow;
#pragma unroll
        for (int ni = 0; ni < 6; ++ni) {
            int o = wcol * 96 + ni * 16 + ocol;
            f32x4 v = acc[mi][ni];
            float* Cp = C + ((size_t)b * CIN + o) * HWPX + pix;
            *(float4*)Cp = make_float4(v[0], v[1], v[2], v[3]);
        }
    }
}

extern "C" void kernel_launch(void* const* d_in, const int* in_sizes, int n_in,
                              void* d_out, int out_size, void* d_ws, size_t ws_size,
                              hipStream_t stream) {
    const float* x = (const float*)d_in[0];
    const float* qkv_w = (const float*)d_in[1];
    const float* dw_w = (const float*)d_in[2];
    const float* proj_w = (const float*)d_in[3];
    const float* temperature = (const float*)d_in[4];
    float* out = (float*)d_out;

    char* ws = (char*)d_ws;
    // layout (bytes), total ~155.3 MB:
    //   [0, 150994944)            pre   bf16 [b][576][16384]
    //   [150994944, +786432)      normp fp32 [bh][8][4][192]
    //   [151781376, +2359296)     gpart fp32
    //   [154140672, +589824)      Mw    bf16
    //   [154730496, +294912)      attb  fp32
    //   [155025408, +221184)      wq    bf16
    ushort_t* pre = (ushort_t*)ws;
    float* normp = (float*)(ws + 150994944);
    float* gpart = (float*)(ws + 151781376);
    ushort_t* Mw = (ushort_t*)(ws + 154140672);
    float* attb = (float*)(ws + 154730496);
    ushort_t* wq = (ushort_t*)(ws + 155025408);

    k_cvtw<<<dim3(108), 256, 0, stream>>>(qkv_w, wq);
    k_gemm<<<dim3(128, 2, 8), 512, 0, stream>>>(x, wq, pre);
    k_gramdw<<<dim3(8, NHEADS, 8), 256, 0, stream>>>(pre, dw_w, gpart, normp);
    k_attn<<<dim3(NHEADS, 8), 256, 0, stream>>>(gpart, normp, temperature, attb);
    k_mw<<<dim3(6, 8), 256, 0, stream>>>(attb, proj_w, Mw);
    k_gemmv<<<dim3(128, 1, 8), 512, 0, stream>>>(pre, dw_w, Mw, out);
}

// Round 10
// 225.084 us; speedup vs baseline: 1.3820x; 1.0751x over previous
//
#include <hip/hip_runtime.h>
#include <hip/hip_bf16.h>

#define CIN 192
#define C3 576
#define HWPX 16384
#define NHEADS 4
#define DH 48

typedef unsigned short ushort_t;
typedef __attribute__((ext_vector_type(8))) short bf16x8;
typedef __attribute__((ext_vector_type(4))) float f32x4;

__device__ __forceinline__ float bf2f(unsigned short u) {
    return __uint_as_float(((unsigned int)u) << 16);
}
__device__ __forceinline__ unsigned short f2bf(float f) {
    unsigned int u = __float_as_uint(f);
    unsigned int r = (u >> 16) & 1u;
    u += 0x7fffu + r;
    return (unsigned short)(u >> 16);
}
__device__ __forceinline__ void up8(uint4 a, float* o) {
    o[0] = __uint_as_float(a.x << 16); o[1] = __uint_as_float(a.x & 0xffff0000u);
    o[2] = __uint_as_float(a.y << 16); o[3] = __uint_as_float(a.y & 0xffff0000u);
    o[4] = __uint_as_float(a.z << 16); o[5] = __uint_as_float(a.z & 0xffff0000u);
    o[6] = __uint_as_float(a.w << 16); o[7] = __uint_as_float(a.w & 0xffff0000u);
}

#define ASYNC_COPY16(gptr, lptr)                                                   \
    __builtin_amdgcn_global_load_lds(                                              \
        (__attribute__((address_space(1))) void*)(gptr),                           \
        (__attribute__((address_space(3))) void*)(lptr), 16, 0, 0)

// ---------------------------------------------------------------------------
// k_cvtw: qkv_w fp32 [576,192] -> bf16 row-major
// ---------------------------------------------------------------------------
__global__ __launch_bounds__(256) void k_cvtw(const float* __restrict__ w,
                                              ushort_t* __restrict__ wb) {
    int i = (blockIdx.x * 256 + threadIdx.x) * 4;
    float4 v = *(const float4*)(w + i);
    uint2 pk;
    pk.x = (unsigned)f2bf(v.x) | ((unsigned)f2bf(v.y) << 16);
    pk.y = (unsigned)f2bf(v.z) | ((unsigned)f2bf(v.w) << 16);
    *(uint2*)(wb + i) = pk;
}

// ---------------------------------------------------------------------------
// k_gemm: pre[o][pix] = sum_k x[k][pix] * wq[o][k]   (MFMA bf16)
// BM=128 pix x BN=192 o (3 o-passes), 512 thr / 8 waves (4x2),
// wave = 32pix x 96o (2x6 frags).
// A-transpose fused: lane (cc,jj) owns px jj+16i (strided) so scatter writes
// spread banks (rows of one store span jj parity) — LDS contents identical
// to the jj*8+i mapping, just different writer lanes.
// ---------------------------------------------------------------------------
__global__ __launch_bounds__(512) void k_gemm(const float* __restrict__ A,
                                              const ushort_t* __restrict__ B,
                                              ushort_t* __restrict__ C) {
    __shared__ ushort_t sA[2][128 * 32];
    __shared__ ushort_t sB[2][192 * 32];
    const int t = threadIdx.x;
    const int lane = t & 63, wave = t >> 6;
    const int wrow = wave >> 1, wcol = wave & 1;
    const int pix0 = blockIdx.x * 128;
    const int o0 = blockIdx.y * 192;
    const int b = blockIdx.z;
    const ushort_t* Bb = B + (size_t)o0 * CIN;

    const int cc = t >> 4;  // channel-in-tile 0..31
    const int jj = t & 15;  // pixel phase 0..15

    float avf[8];
    auto loadA = [&](int kc) {
        const float* Ab = A + (size_t)b * CIN * HWPX +
                          (size_t)(kc + cc) * HWPX + pix0 + jj;
#pragma unroll
        for (int i = 0; i < 8; ++i) avf[i] = Ab[16 * i];
    };
    auto writeA = [&](int buf) {
        ushort_t* s = sA[buf];
#pragma unroll
        for (int i = 0; i < 8; ++i) {
            int row = jj + 16 * i;
            int slot = ((cc >> 3) + (row >> 1) + (row >> 3)) & 3;
            s[row * 32 + slot * 8 + (cc & 7)] = f2bf(avf[i]);
        }
    };
    auto stageB = [&](int buf, int kc) {
        {
            int row = t >> 2, slot = t & 3;
            int g = (slot + (row >> 1)) & 3;
            const ushort_t* gp = Bb + (size_t)row * CIN + kc + g * 8;
            ushort_t* lp = &sB[buf][(wave * 64) * 8];
            ASYNC_COPY16(gp, lp);
        }
        if (t < 256) {
            int e = 512 + t;
            int row = e >> 2, slot = e & 3;
            int g = (slot + (row >> 1)) & 3;
            const ushort_t* gp = Bb + (size_t)row * CIN + kc + g * 8;
            ushort_t* lp = &sB[buf][(512 + wave * 64) * 8];
            ASYNC_COPY16(gp, lp);
        }
    };

    f32x4 acc[2][6];
#pragma unroll
    for (int mi = 0; mi < 2; ++mi)
#pragma unroll
        for (int ni = 0; ni < 6; ++ni) acc[mi][ni] = (f32x4){0.f, 0.f, 0.f, 0.f};

    loadA(0);
    writeA(0);
    stageB(0, 0);
#pragma unroll
    for (int ks = 0; ks < 6; ++ks) {
        __syncthreads();
        const int buf = ks & 1;
        if (ks < 5) {
            loadA((ks + 1) * 32);
            stageB(buf ^ 1, (ks + 1) * 32);
        }
        const ushort_t* a_ = sA[buf];
        const ushort_t* b_ = sB[buf];
        const int c = lane >> 4;
        bf16x8 af[2], bfr[6];
#pragma unroll
        for (int mi = 0; mi < 2; ++mi) {
            int row = wrow * 32 + mi * 16 + (lane & 15);
            int slot = (c + (row >> 1) + (row >> 3)) & 3;
            af[mi] = *(const bf16x8*)&a_[row * 32 + slot * 8];
        }
#pragma unroll
        for (int ni = 0; ni < 6; ++ni) {
            int row = wcol * 96 + ni * 16 + (lane & 15);
            int slot = (c - (row >> 1)) & 3;
            bfr[ni] = *(const bf16x8*)&b_[row * 32 + slot * 8];
        }
#pragma unroll
        for (int mi = 0; mi < 2; ++mi)
#pragma unroll
            for (int ni = 0; ni < 6; ++ni)
                acc[mi][ni] = __builtin_amdgcn_mfma_f32_16x16x32_bf16(
                    af[mi], bfr[ni], acc[mi][ni], 0, 0, 0);
        if (ks < 5) writeA(buf ^ 1);
    }

    const int ocol = lane & 15;
    const int prow = (lane >> 4) * 4;
#pragma unroll
    for (int mi = 0; mi < 2; ++mi) {
        int pix = pix0 + wrow * 32 + mi * 16 + prow;
#pragma unroll
        for (int ni = 0; ni < 6; ++ni) {
            int o = o0 + wcol * 96 + ni * 16 + ocol;
            f32x4 v = acc[mi][ni];
            ushort_t* Cp = C + ((size_t)b * C3 + o) * HWPX + pix;
            uint2 pk;
            pk.x = (unsigned)f2bf(v[0]) | ((unsigned)f2bf(v[1]) << 16);
            pk.y = (unsigned)f2bf(v[2]) | ((unsigned)f2bf(v[3]) << 16);
            *(uint2*)Cp = pk;
        }
    }
}

// ---------------------------------------------------------------------------
// k_gramdw: fused {3x3 dw conv on q,k} + {gram partials} + {ssq partials}
// grid (chunk=8, h=4, b=8), 256 thr / 4 waves. Wave = 32-px column strip,
// y slides chunk*16 .. +15; ring of 3 rows in regs, 1-row prefetch.
// ---------------------------------------------------------------------------
__global__ __launch_bounds__(256, 1) void k_gramdw(const ushort_t* __restrict__ pre,
                                                   const float* __restrict__ dww,
                                                   float* __restrict__ gpart,
                                                   float* __restrict__ normp) {
    __shared__ char smem[NHEADS * DH * DH * 4];  // 36864 B: sC (30720) / sG union
    ushort_t* sCw = (ushort_t*)smem + (threadIdx.x >> 6) * (96 * 40);
    float* sG = (float*)smem;

    const int chunk = blockIdx.x, h = blockIdx.y, b = blockIdx.z;
    const int t = threadIdx.x;
    const int lane = t & 63, wave = t >> 6;
    const int y0 = chunk * 16;

    const ushort_t* plane[3];
    float wreg[3][9];
    int pxb[3];
#pragma unroll
    for (int u = 0; u < 3; ++u) {
        int id = lane + 64 * u;
        int c96 = id >> 1;
        int gch = (c96 < DH) ? (h * DH + c96) : (CIN + h * DH + (c96 - DH));
        plane[u] = pre + ((size_t)b * C3 + gch) * HWPX;
        pxb[u] = wave * 32 + (id & 1) * 16;
#pragma unroll
        for (int k = 0; k < 9; ++k) wreg[u][k] = dww[gch * 9 + k];
    }

    float ssq[3] = {0.f, 0.f, 0.f};
    f32x4 acc[3][3];
#pragma unroll
    for (int i = 0; i < 3; ++i)
#pragma unroll
        for (int j = 0; j < 3; ++j) acc[i][j] = (f32x4){0.f, 0.f, 0.f, 0.f};

    uint4 ring[3][3][2];
    ushort_t lfr[3][3], rgr[3][3];
    uint4 nx[3][2];
    ushort_t nlf[3], nrg[3];

    auto LOADROW = [&](int YY) {
#pragma unroll
        for (int u = 0; u < 3; ++u) {
            bool ok = ((unsigned)YY < 128u);
            const ushort_t* rp = plane[u] + YY * 128 + pxb[u];
            if (ok) {
                nx[u][0] = *(const uint4*)rp;
                nx[u][1] = *(const uint4*)(rp + 8);
                nlf[u] = (pxb[u] > 0) ? rp[-1] : (ushort_t)0;
                nrg[u] = (pxb[u] + 16 < 128) ? rp[16] : (ushort_t)0;
            } else {
                nx[u][0] = make_uint4(0, 0, 0, 0);
                nx[u][1] = make_uint4(0, 0, 0, 0);
                nlf[u] = 0;
                nrg[u] = 0;
            }
        }
    };
    auto PUT = [&](int rp) {
#pragma unroll
        for (int u = 0; u < 3; ++u) {
            ring[rp][u][0] = nx[u][0];
            ring[rp][u][1] = nx[u][1];
            lfr[rp][u] = nlf[u];
            rgr[rp][u] = nrg[u];
        }
    };

    LOADROW(y0 - 1); PUT(0);
    LOADROW(y0);     PUT(1);
    LOADROW(y0 + 1); PUT(2);

    for (int s = 0; s < 16; ++s) {
        if (s < 15) LOADROW(y0 + s + 2);
#pragma unroll
        for (int u = 0; u < 3; ++u) {
            int id = lane + 64 * u;
            float in[3][18];
#pragma unroll
            for (int r = 0; r < 3; ++r) {
                in[r][0] = bf2f(lfr[r][u]);
                up8(ring[r][u][0], &in[r][1]);
                up8(ring[r][u][1], &in[r][9]);
                in[r][17] = bf2f(rgr[r][u]);
            }
            unsigned pk[8];
#pragma unroll
            for (int j2 = 0; j2 < 8; ++j2) {
                float o0 = 0.f, o1 = 0.f;
#pragma unroll
                for (int ky = 0; ky < 3; ++ky) {
                    o0 = fmaf(wreg[u][ky * 3 + 0], in[ky][2 * j2 + 0], o0);
                    o0 = fmaf(wreg[u][ky * 3 + 1], in[ky][2 * j2 + 1], o0);
                    o0 = fmaf(wreg[u][ky * 3 + 2], in[ky][2 * j2 + 2], o0);
                    o1 = fmaf(wreg[u][ky * 3 + 0], in[ky][2 * j2 + 1], o1);
                    o1 = fmaf(wreg[u][ky * 3 + 1], in[ky][2 * j2 + 2], o1);
                    o1 = fmaf(wreg[u][ky * 3 + 2], in[ky][2 * j2 + 3], o1);
                }
                ssq[u] = fmaf(o0, o0, ssq[u]);
                ssq[u] = fmaf(o1, o1, ssq[u]);
                pk[j2] = (unsigned)f2bf(o0) | ((unsigned)f2bf(o1) << 16);
            }
            uint4* dst = (uint4*)&sCw[(id >> 1) * 40 + ((id & 1) << 4)];
            dst[0] = make_uint4(pk[0], pk[1], pk[2], pk[3]);
            dst[1] = make_uint4(pk[4], pk[5], pk[6], pk[7]);
        }
        {
            bf16x8 af[3], bk[3];
#pragma unroll
            for (int i = 0; i < 3; ++i)
                af[i] = *(const bf16x8*)&sCw[(i * 16 + (lane & 15)) * 40 + (lane >> 4) * 8];
#pragma unroll
            for (int j = 0; j < 3; ++j)
                bk[j] = *(const bf16x8*)&sCw[(48 + j * 16 + (lane & 15)) * 40 + (lane >> 4) * 8];
#pragma unroll
            for (int i = 0; i < 3; ++i)
#pragma unroll
                for (int j = 0; j < 3; ++j)
                    acc[i][j] = __builtin_amdgcn_mfma_f32_16x16x32_bf16(af[i], bk[j],
                                                                        acc[i][j], 0, 0, 0);
        }
        if (s < 15) {
#pragma unroll
            for (int u = 0; u < 3; ++u) {
                ring[0][u][0] = ring[1][u][0]; ring[0][u][1] = ring[1][u][1];
                ring[1][u][0] = ring[2][u][0]; ring[1][u][1] = ring[2][u][1];
                ring[2][u][0] = nx[u][0];      ring[2][u][1] = nx[u][1];
                lfr[0][u] = lfr[1][u]; lfr[1][u] = lfr[2][u]; lfr[2][u] = nlf[u];
                rgr[0][u] = rgr[1][u]; rgr[1][u] = rgr[2][u]; rgr[2][u] = nrg[u];
            }
        }
    }

    __syncthreads();
    const int crow = (lane >> 4) * 4;
    const int dcol = lane & 15;
#pragma unroll
    for (int i = 0; i < 3; ++i)
#pragma unroll
        for (int j = 0; j < 3; ++j)
#pragma unroll
            for (int r = 0; r < 4; ++r)
                sG[(size_t)wave * DH * DH + (i * 16 + crow + r) * DH + j * 16 + dcol] =
                    acc[i][j][r];
    __syncthreads();
    float* g = gpart + (((size_t)(b * NHEADS + h)) * 8 + chunk) * (DH * DH);
    for (int e = t; e < DH * DH; e += 256)
        g[e] = sG[e] + sG[DH * DH + e] + sG[2 * DH * DH + e] + sG[3 * DH * DH + e];

    float* np = normp + ((((size_t)(b * NHEADS + h)) * 8 + chunk) * 4 + wave) * 192;
#pragma unroll
    for (int u = 0; u < 3; ++u) np[lane + 64 * u] = ssq[u];
}

// ---------------------------------------------------------------------------
// k_attn: sum gram+norm partials -> normalize -> softmax -> att fp32
// ---------------------------------------------------------------------------
__global__ __launch_bounds__(256) void k_attn(const float* __restrict__ gpart,
                                              const float* __restrict__ normp,
                                              const float* __restrict__ temperature,
                                              float* __restrict__ att) {
    __shared__ float sA[DH][DH + 1];
    __shared__ float nrm[96];
    const int h = blockIdx.x, b = blockIdx.y;
    const int t = threadIdx.x;
    const size_t bh = b * NHEADS + h;
    if (t < 96) {
        float s = 0.f;
        for (int ck = 0; ck < 8; ++ck)
#pragma unroll
            for (int w = 0; w < 4; ++w) {
                const float* np = normp + ((bh * 8 + ck) * 4 + w) * 192 + t * 2;
                s += np[0] + np[1];
            }
        nrm[t] = fmaxf(sqrtf(s), 1e-12f);
    }
    __syncthreads();
    const float* base = gpart + (bh * 8) * (DH * DH);
    for (int e = t; e < DH * DH; e += 256) {
        float s = 0.f;
#pragma unroll
        for (int c8 = 0; c8 < 8; ++c8) s += base[(size_t)c8 * DH * DH + e];
        int c = e / DH, d = e % DH;
        sA[c][d] = s / (nrm[c] * nrm[48 + d]) * temperature[h];
    }
    __syncthreads();
    if (t < DH) {
        float m = -1e30f;
#pragma unroll
        for (int d = 0; d < DH; ++d) m = fmaxf(m, sA[t][d]);
        float s = 0.f;
        float row[DH];
#pragma unroll
        for (int d = 0; d < DH; ++d) {
            row[d] = expf(sA[t][d] - m);
            s += row[d];
        }
        float inv = 1.f / s;
#pragma unroll
        for (int d = 0; d < DH; ++d) sA[t][d] = row[d] * inv;
    }
    __syncthreads();
    float* ob = att + bh * DH * DH;
    for (int e = t; e < DH * DH; e += 256) ob[e] = sA[e / DH][e % DH];
}

// ---------------------------------------------------------------------------
// k_mw: Mw[b][o][192] = proj_w @ blockdiag(att), bf16 out. grid (6 otile, b)
// ---------------------------------------------------------------------------
__global__ __launch_bounds__(256) void k_mw(const float* __restrict__ att,
                                            const float* __restrict__ proj_w,
                                            ushort_t* __restrict__ Mw) {
    __shared__ float satt[NHEADS][DH][DH];
    __shared__ float sproj[32][CIN];
    const int o0 = blockIdx.x * 32, b = blockIdx.y;
    const int t = threadIdx.x;
    {
        const float4* src = (const float4*)(att + (size_t)b * NHEADS * DH * DH);
        float4* dst = (float4*)&satt[0][0][0];
        for (int e = t; e < NHEADS * DH * DH / 4; e += 256) dst[e] = src[e];
        const float4* ps = (const float4*)(proj_w + (size_t)o0 * CIN);
        float4* pd = (float4*)&sproj[0][0];
        for (int e = t; e < 32 * CIN / 4; e += 256) pd[e] = ps[e];
    }
    __syncthreads();
    ushort_t* ob = Mw + (size_t)b * CIN * CIN + (size_t)o0 * CIN;
    for (int e = t; e < 32 * CIN; e += 256) {
        int o = e / CIN, dg = e % CIN;
        int h = dg / DH, d = dg % DH;
        float s = 0.f;
#pragma unroll
        for (int c = 0; c < DH; ++c) s = fmaf(sproj[o][h * DH + c], satt[h][c][d], s);
        ob[e] = f2bf(s);
    }
}

// ---------------------------------------------------------------------------
// k_gemmv: out[o][pix] = sum_ch Mw[o][ch] * dw3x3(v)[ch][pix]
// dw conv fused into A-staging (reads raw pre v-planes + row halo).
// BM=128 (one image row), BN=192 (all o), 512 thr / 8 waves.
// ---------------------------------------------------------------------------
__global__ __launch_bounds__(512) void k_gemmv(const ushort_t* __restrict__ pre,
                                               const float* __restrict__ dww,
                                               const ushort_t* __restrict__ B,
                                               float* __restrict__ C) {
    __shared__ ushort_t sA[2][128 * 32];
    __shared__ ushort_t sB[2][192 * 32];
    const int t = threadIdx.x;
    const int lane = t & 63, wave = t >> 6;
    const int wrow = wave >> 1, wcol = wave & 1;
    const int Y = blockIdx.x;
    const int pix0 = Y * 128;
    const int b = blockIdx.z;
    const ushort_t* Bb = B + (size_t)b * CIN * CIN;

    const int cc = t >> 4;
    const int jj = t & 15;
    const int x0 = jj * 8;

    uint4 m[3];
    ushort_t l16[3], rg16[3];
    float wv[9];
    ushort_t av[8];

    auto loadV = [&](int kc) {
        int ch = kc + cc;
        const ushort_t* pl = pre + ((size_t)b * C3 + 2 * CIN + ch) * HWPX;
#pragma unroll
        for (int r = 0; r < 3; ++r) {
            int YY = Y - 1 + r;
            bool ok = ((unsigned)YY < 128u);
            const ushort_t* rp = pl + YY * 128;
            if (ok) {
                m[r] = *(const uint4*)(rp + x0);
                l16[r] = (x0 > 0) ? rp[x0 - 1] : (ushort_t)0;
                rg16[r] = (x0 < 120) ? rp[x0 + 8] : (ushort_t)0;
            } else {
                m[r] = make_uint4(0, 0, 0, 0);
                l16[r] = 0;
                rg16[r] = 0;
            }
        }
#pragma unroll
        for (int k = 0; k < 9; ++k) wv[k] = dww[(2 * CIN + ch) * 9 + k];
    };
    auto convV = [&]() {
        float in[3][10];
#pragma unroll
        for (int r = 0; r < 3; ++r) {
            in[r][0] = bf2f(l16[r]);
            up8(m[r], &in[r][1]);
            in[r][9] = bf2f(rg16[r]);
        }
#pragma unroll
        for (int j = 0; j < 8; ++j) {
            float o = 0.f;
#pragma unroll
            for (int ky = 0; ky < 3; ++ky) {
                o = fmaf(wv[ky * 3 + 0], in[ky][j + 0], o);
                o = fmaf(wv[ky * 3 + 1], in[ky][j + 1], o);
                o = fmaf(wv[ky * 3 + 2], in[ky][j + 2], o);
            }
            av[j] = f2bf(o);
        }
    };
    auto writeA = [&](int buf) {
        ushort_t* s = sA[buf];
#pragma unroll
        for (int i = 0; i < 8; ++i) {
            int row = jj * 8 + i;
            int slot = ((cc >> 3) + (row >> 1) + (row >> 3)) & 3;
            s[row * 32 + slot * 8 + (cc & 7)] = av[i];
        }
    };
    auto stageB = [&](int buf, int kc) {
        {
            int row = t >> 2, slot = t & 3;
            int g = (slot + (row >> 1)) & 3;
            const ushort_t* gp = Bb + (size_t)row * CIN + kc + g * 8;
            ushort_t* lp = &sB[buf][(wave * 64) * 8];
            ASYNC_COPY16(gp, lp);
        }
        if (t < 256) {
            int e = 512 + t;
            int row = e >> 2, slot = e & 3;
            int g = (slot + (row >> 1)) & 3;
            const ushort_t* gp = Bb + (size_t)row * CIN + kc + g * 8;
            ushort_t* lp = &sB[buf][(512 + wave * 64) * 8];
            ASYNC_COPY16(gp, lp);
        }
    };

    f32x4 acc[2][6];
#pragma unroll
    for (int mi = 0; mi < 2; ++mi)
#pragma unroll
        for (int ni = 0; ni < 6; ++ni) acc[mi][ni] = (f32x4){0.f, 0.f, 0.f, 0.f};

    loadV(0);
    convV();
    writeA(0);
    stageB(0, 0);
#pragma unroll
    for (int ks = 0; ks < 6; ++ks) {
        __syncthreads();
        const int buf = ks & 1;
        if (ks < 5) {
            loadV((ks + 1) * 32);
            stageB(buf ^ 1, (ks + 1) * 32);
        }
        const ushort_t* a_ = sA[buf];
        const ushort_t* b_ = sB[buf];
        const int c = lane >> 4;
        bf16x8 af[2], bfr[6];
#pragma unroll
        for (int mi = 0; mi < 2; ++mi) {
            int row = wrow * 32 + mi * 16 + (lane & 15);
            int slot = (c + (row >> 1) + (row >> 3)) & 3;
            af[mi] = *(const bf16x8*)&a_[row * 32 + slot * 8];
        }
#pragma unroll
        for (int ni = 0; ni < 6; ++ni) {
            int row = wcol * 96 + ni * 16 + (lane & 15);
            int slot = (c - (row >> 1)) & 3;
            bfr[ni] = *(const bf16x8*)&b_[row * 32 + slot * 8];
        }
#pragma unroll
        for (int mi = 0; mi < 2; ++mi)
#pragma unroll
            for (int ni = 0; ni < 6; ++ni)
                acc[mi][ni] = __builtin_amdgcn_mfma_f32_16x16x32_bf16(
                    af[mi], bfr[ni], acc[mi][ni], 0, 0, 0);
        if (ks < 5) {
            convV();
            writeA(buf ^ 1);
        }
    }

    const int ocol = lane & 15;
    const int prow = (lane >> 4) * 4;
#pragma unroll
    for (int mi = 0; mi < 2; ++mi) {
        int pix = pix0 + wrow * 32 + mi * 16 + prow;
#pragma unroll
        for (int ni = 0; ni < 6; ++ni) {
            int o = wcol * 96 + ni * 16 + ocol;
            f32x4 v = acc[mi][ni];
            float* Cp = C + ((size_t)b * CIN + o) * HWPX + pix;
            *(float4*)Cp = make_float4(v[0], v[1], v[2], v[3]);
        }
    }
}

extern "C" void kernel_launch(void* const* d_in, const int* in_sizes, int n_in,
                              void* d_out, int out_size, void* d_ws, size_t ws_size,
                              hipStream_t stream) {
    const float* x = (const float*)d_in[0];
    const float* qkv_w = (const float*)d_in[1];
    const float* dw_w = (const float*)d_in[2];
    const float* proj_w = (const float*)d_in[3];
    const float* temperature = (const float*)d_in[4];
    float* out = (float*)d_out;

    char* ws = (char*)d_ws;
    ushort_t* pre = (ushort_t*)ws;
    float* normp = (float*)(ws + 150994944);
    float* gpart = (float*)(ws + 151781376);
    ushort_t* Mw = (ushort_t*)(ws + 154140672);
    float* attb = (float*)(ws + 154730496);
    ushort_t* wq = (ushort_t*)(ws + 155025408);

    k_cvtw<<<dim3(108), 256, 0, stream>>>(qkv_w, wq);
    k_gemm<<<dim3(128, 3, 8), 512, 0, stream>>>(x, wq, pre);
    k_gramdw<<<dim3(8, NHEADS, 8), 256, 0, stream>>>(pre, dw_w, gpart, normp);
    k_attn<<<dim3(NHEADS, 8), 256, 0, stream>>>(gpart, normp, temperature, attb);
    k_mw<<<dim3(6, 8), 256, 0, stream>>>(attb, proj_w, Mw);
    k_gemmv<<<dim3(128, 1, 8), 512, 0, stream>>>(pre, dw_w, Mw, out);
}

// Round 11
// 212.679 us; speedup vs baseline: 1.4626x; 1.0583x over previous
//
#include <hip/hip_runtime.h>
#include <hip/hip_bf16.h>

#define CIN 192
#define C3 576
#define HWPX 16384
#define NHEADS 4
#define DH 48

typedef unsigned short ushort_t;
typedef __attribute__((ext_vector_type(8))) short bf16x8;
typedef __attribute__((ext_vector_type(4))) float f32x4;

__device__ __forceinline__ float bf2f(unsigned short u) {
    return __uint_as_float(((unsigned int)u) << 16);
}
__device__ __forceinline__ unsigned short f2bf(float f) {
    unsigned int u = __float_as_uint(f);
    unsigned int r = (u >> 16) & 1u;
    u += 0x7fffu + r;
    return (unsigned short)(u >> 16);
}
__device__ __forceinline__ void up8(uint4 a, float* o) {
    o[0] = __uint_as_float(a.x << 16); o[1] = __uint_as_float(a.x & 0xffff0000u);
    o[2] = __uint_as_float(a.y << 16); o[3] = __uint_as_float(a.y & 0xffff0000u);
    o[4] = __uint_as_float(a.z << 16); o[5] = __uint_as_float(a.z & 0xffff0000u);
    o[6] = __uint_as_float(a.w << 16); o[7] = __uint_as_float(a.w & 0xffff0000u);
}

#define ASYNC_COPY16(gptr, lptr)                                                   \
    __builtin_amdgcn_global_load_lds(                                              \
        (__attribute__((address_space(1))) void*)(gptr),                           \
        (__attribute__((address_space(3))) void*)(lptr), 16, 0, 0)

// ---------------------------------------------------------------------------
// k_cvtw: qkv_w fp32 [576,192] -> bf16 row-major
// ---------------------------------------------------------------------------
__global__ __launch_bounds__(256) void k_cvtw(const float* __restrict__ w,
                                              ushort_t* __restrict__ wb) {
    int i = (blockIdx.x * 256 + threadIdx.x) * 4;
    float4 v = *(const float4*)(w + i);
    uint2 pk;
    pk.x = (unsigned)f2bf(v.x) | ((unsigned)f2bf(v.y) << 16);
    pk.y = (unsigned)f2bf(v.z) | ((unsigned)f2bf(v.w) << 16);
    *(uint2*)(wb + i) = pk;
}

// ---------------------------------------------------------------------------
// k_gemm: pre[o][pix] = sum_k x[k][pix] * wq[o][k]   (MFMA bf16)
// Full-K A tile (128px x 192K, 48KB) staged ONCE per block; then 3 o-group
// passes x 6 K-steps each {dbuf stageB, 12 MFMA/wave} reuse it.
// 512 thr / 8 waves (4x2), wave = 32px x 96o (2x6 frags).
// ---------------------------------------------------------------------------
__global__ __launch_bounds__(512) void k_gemm(const float* __restrict__ A,
                                              const ushort_t* __restrict__ B,
                                              ushort_t* __restrict__ C) {
    __shared__ ushort_t sA[6 * 128 * 32];     // 48 KB, chunk c at c*4096
    __shared__ ushort_t sB[2][192 * 32];      // 24 KB
    const int t = threadIdx.x;
    const int lane = t & 63, wave = t >> 6;
    const int wrow = wave >> 1, wcol = wave & 1;
    const int pix0 = blockIdx.x * 128;
    const int b = blockIdx.z;

    const int cc = t >> 4;  // channel-in-chunk 0..31
    const int jj = t & 15;  // pixel phase 0..15

    // ---- stage full-K A once ----
    {
        float avf[6][8];
#pragma unroll
        for (int c = 0; c < 6; ++c) {
            const float* Ab = A + (size_t)b * CIN * HWPX +
                              (size_t)(c * 32 + cc) * HWPX + pix0 + jj;
#pragma unroll
            for (int i = 0; i < 8; ++i) avf[c][i] = Ab[16 * i];
        }
#pragma unroll
        for (int c = 0; c < 6; ++c) {
            ushort_t* s = &sA[c * 4096];
#pragma unroll
            for (int i = 0; i < 8; ++i) {
                int row = jj + 16 * i;
                int slot = ((cc >> 3) + (row >> 1) + (row >> 3)) & 3;
                s[row * 32 + slot * 8 + (cc & 7)] = f2bf(avf[c][i]);
            }
        }
    }

    auto stageB = [&](int buf, int og, int kc) {
        const ushort_t* Bb = B + (size_t)og * 192 * CIN;
        {
            int row = t >> 2, slot = t & 3;
            int g = (slot + (row >> 1)) & 3;
            const ushort_t* gp = Bb + (size_t)row * CIN + kc + g * 8;
            ushort_t* lp = &sB[buf][(wave * 64) * 8];
            ASYNC_COPY16(gp, lp);
        }
        if (t < 256) {
            int e = 512 + t;
            int row = e >> 2, slot = e & 3;
            int g = (slot + (row >> 1)) & 3;
            const ushort_t* gp = Bb + (size_t)row * CIN + kc + g * 8;
            ushort_t* lp = &sB[buf][(512 + wave * 64) * 8];
            ASYNC_COPY16(gp, lp);
        }
    };

    f32x4 acc[2][6];
#pragma unroll
    for (int mi = 0; mi < 2; ++mi)
#pragma unroll
        for (int ni = 0; ni < 6; ++ni) acc[mi][ni] = (f32x4){0.f, 0.f, 0.f, 0.f};

    stageB(0, 0, 0);

    const int ocol = lane & 15;
    const int prow = (lane >> 4) * 4;
    const int c = lane >> 4;

#pragma unroll
    for (int og = 0; og < 3; ++og) {
#pragma unroll
        for (int ks = 0; ks < 6; ++ks) {
            const int step = og * 6 + ks;
            const int buf = step & 1;
            __syncthreads();
            if (step + 1 < 18)
                stageB(buf ^ 1, (step + 1) / 6, ((step + 1) % 6) * 32);
            const ushort_t* a_ = &sA[ks * 4096];
            const ushort_t* b_ = sB[buf];
            bf16x8 af[2], bfr[6];
#pragma unroll
            for (int mi = 0; mi < 2; ++mi) {
                int row = wrow * 32 + mi * 16 + (lane & 15);
                int slot = (c + (row >> 1) + (row >> 3)) & 3;
                af[mi] = *(const bf16x8*)&a_[row * 32 + slot * 8];
            }
#pragma unroll
            for (int ni = 0; ni < 6; ++ni) {
                int row = wcol * 96 + ni * 16 + (lane & 15);
                int slot = (c - (row >> 1)) & 3;
                bfr[ni] = *(const bf16x8*)&b_[row * 32 + slot * 8];
            }
#pragma unroll
            for (int mi = 0; mi < 2; ++mi)
#pragma unroll
                for (int ni = 0; ni < 6; ++ni)
                    acc[mi][ni] = __builtin_amdgcn_mfma_f32_16x16x32_bf16(
                        af[mi], bfr[ni], acc[mi][ni], 0, 0, 0);
        }
        // epilogue for this o-group
#pragma unroll
        for (int mi = 0; mi < 2; ++mi) {
            int pix = pix0 + wrow * 32 + mi * 16 + prow;
#pragma unroll
            for (int ni = 0; ni < 6; ++ni) {
                int o = og * 192 + wcol * 96 + ni * 16 + ocol;
                f32x4 v = acc[mi][ni];
                ushort_t* Cp = C + ((size_t)b * C3 + o) * HWPX + pix;
                uint2 pk;
                pk.x = (unsigned)f2bf(v[0]) | ((unsigned)f2bf(v[1]) << 16);
                pk.y = (unsigned)f2bf(v[2]) | ((unsigned)f2bf(v[3]) << 16);
                *(uint2*)Cp = pk;
                acc[mi][ni] = (f32x4){0.f, 0.f, 0.f, 0.f};
            }
        }
    }
}

// ---------------------------------------------------------------------------
// k_gramdw: fused {3x3 dw conv on q,k} + {gram partials} + {ssq partials}
// grid (chunk=8, h=4, b=8), 256 thr / 4 waves. Wave = 32-px column strip,
// y slides chunk*16 .. +15; ring of 3 rows in regs, 1-row prefetch.
// ---------------------------------------------------------------------------
__global__ __launch_bounds__(256, 1) void k_gramdw(const ushort_t* __restrict__ pre,
                                                   const float* __restrict__ dww,
                                                   float* __restrict__ gpart,
                                                   float* __restrict__ normp) {
    __shared__ char smem[NHEADS * DH * DH * 4];  // 36864 B: sC (30720) / sG union
    ushort_t* sCw = (ushort_t*)smem + (threadIdx.x >> 6) * (96 * 40);
    float* sG = (float*)smem;

    const int chunk = blockIdx.x, h = blockIdx.y, b = blockIdx.z;
    const int t = threadIdx.x;
    const int lane = t & 63, wave = t >> 6;
    const int y0 = chunk * 16;

    const ushort_t* plane[3];
    float wreg[3][9];
    int pxb[3];
#pragma unroll
    for (int u = 0; u < 3; ++u) {
        int id = lane + 64 * u;
        int c96 = id >> 1;
        int gch = (c96 < DH) ? (h * DH + c96) : (CIN + h * DH + (c96 - DH));
        plane[u] = pre + ((size_t)b * C3 + gch) * HWPX;
        pxb[u] = wave * 32 + (id & 1) * 16;
#pragma unroll
        for (int k = 0; k < 9; ++k) wreg[u][k] = dww[gch * 9 + k];
    }

    float ssq[3] = {0.f, 0.f, 0.f};
    f32x4 acc[3][3];
#pragma unroll
    for (int i = 0; i < 3; ++i)
#pragma unroll
        for (int j = 0; j < 3; ++j) acc[i][j] = (f32x4){0.f, 0.f, 0.f, 0.f};

    uint4 ring[3][3][2];
    ushort_t lfr[3][3], rgr[3][3];
    uint4 nx[3][2];
    ushort_t nlf[3], nrg[3];

    auto LOADROW = [&](int YY) {
#pragma unroll
        for (int u = 0; u < 3; ++u) {
            bool ok = ((unsigned)YY < 128u);
            const ushort_t* rp = plane[u] + YY * 128 + pxb[u];
            if (ok) {
                nx[u][0] = *(const uint4*)rp;
                nx[u][1] = *(const uint4*)(rp + 8);
                nlf[u] = (pxb[u] > 0) ? rp[-1] : (ushort_t)0;
                nrg[u] = (pxb[u] + 16 < 128) ? rp[16] : (ushort_t)0;
            } else {
                nx[u][0] = make_uint4(0, 0, 0, 0);
                nx[u][1] = make_uint4(0, 0, 0, 0);
                nlf[u] = 0;
                nrg[u] = 0;
            }
        }
    };
    auto PUT = [&](int rp) {
#pragma unroll
        for (int u = 0; u < 3; ++u) {
            ring[rp][u][0] = nx[u][0];
            ring[rp][u][1] = nx[u][1];
            lfr[rp][u] = nlf[u];
            rgr[rp][u] = nrg[u];
        }
    };

    LOADROW(y0 - 1); PUT(0);
    LOADROW(y0);     PUT(1);
    LOADROW(y0 + 1); PUT(2);

    for (int s = 0; s < 16; ++s) {
        if (s < 15) LOADROW(y0 + s + 2);
#pragma unroll
        for (int u = 0; u < 3; ++u) {
            int id = lane + 64 * u;
            float in[3][18];
#pragma unroll
            for (int r = 0; r < 3; ++r) {
                in[r][0] = bf2f(lfr[r][u]);
                up8(ring[r][u][0], &in[r][1]);
                up8(ring[r][u][1], &in[r][9]);
                in[r][17] = bf2f(rgr[r][u]);
            }
            unsigned pk[8];
#pragma unroll
            for (int j2 = 0; j2 < 8; ++j2) {
                float o0 = 0.f, o1 = 0.f;
#pragma unroll
                for (int ky = 0; ky < 3; ++ky) {
                    o0 = fmaf(wreg[u][ky * 3 + 0], in[ky][2 * j2 + 0], o0);
                    o0 = fmaf(wreg[u][ky * 3 + 1], in[ky][2 * j2 + 1], o0);
                    o0 = fmaf(wreg[u][ky * 3 + 2], in[ky][2 * j2 + 2], o0);
                    o1 = fmaf(wreg[u][ky * 3 + 0], in[ky][2 * j2 + 1], o1);
                    o1 = fmaf(wreg[u][ky * 3 + 1], in[ky][2 * j2 + 2], o1);
                    o1 = fmaf(wreg[u][ky * 3 + 2], in[ky][2 * j2 + 3], o1);
                }
                ssq[u] = fmaf(o0, o0, ssq[u]);
                ssq[u] = fmaf(o1, o1, ssq[u]);
                pk[j2] = (unsigned)f2bf(o0) | ((unsigned)f2bf(o1) << 16);
            }
            uint4* dst = (uint4*)&sCw[(id >> 1) * 40 + ((id & 1) << 4)];
            dst[0] = make_uint4(pk[0], pk[1], pk[2], pk[3]);
            dst[1] = make_uint4(pk[4], pk[5], pk[6], pk[7]);
        }
        {
            bf16x8 af[3], bk[3];
#pragma unroll
            for (int i = 0; i < 3; ++i)
                af[i] = *(const bf16x8*)&sCw[(i * 16 + (lane & 15)) * 40 + (lane >> 4) * 8];
#pragma unroll
            for (int j = 0; j < 3; ++j)
                bk[j] = *(const bf16x8*)&sCw[(48 + j * 16 + (lane & 15)) * 40 + (lane >> 4) * 8];
#pragma unroll
            for (int i = 0; i < 3; ++i)
#pragma unroll
                for (int j = 0; j < 3; ++j)
                    acc[i][j] = __builtin_amdgcn_mfma_f32_16x16x32_bf16(af[i], bk[j],
                                                                        acc[i][j], 0, 0, 0);
        }
        if (s < 15) {
#pragma unroll
            for (int u = 0; u < 3; ++u) {
                ring[0][u][0] = ring[1][u][0]; ring[0][u][1] = ring[1][u][1];
                ring[1][u][0] = ring[2][u][0]; ring[1][u][1] = ring[2][u][1];
                ring[2][u][0] = nx[u][0];      ring[2][u][1] = nx[u][1];
                lfr[0][u] = lfr[1][u]; lfr[1][u] = lfr[2][u]; lfr[2][u] = nlf[u];
                rgr[0][u] = rgr[1][u]; rgr[1][u] = rgr[2][u]; rgr[2][u] = nrg[u];
            }
        }
    }

    __syncthreads();
    const int crow = (lane >> 4) * 4;
    const int dcol = lane & 15;
#pragma unroll
    for (int i = 0; i < 3; ++i)
#pragma unroll
        for (int j = 0; j < 3; ++j)
#pragma unroll
            for (int r = 0; r < 4; ++r)
                sG[(size_t)wave * DH * DH + (i * 16 + crow + r) * DH + j * 16 + dcol] =
                    acc[i][j][r];
    __syncthreads();
    float* g = gpart + (((size_t)(b * NHEADS + h)) * 8 + chunk) * (DH * DH);
    for (int e = t; e < DH * DH; e += 256)
        g[e] = sG[e] + sG[DH * DH + e] + sG[2 * DH * DH + e] + sG[3 * DH * DH + e];

    float* np = normp + ((((size_t)(b * NHEADS + h)) * 8 + chunk) * 4 + wave) * 192;
#pragma unroll
    for (int u = 0; u < 3; ++u) np[lane + 64 * u] = ssq[u];
}

// ---------------------------------------------------------------------------
// k_attn: sum gram+norm partials -> normalize -> softmax -> att fp32
// ---------------------------------------------------------------------------
__global__ __launch_bounds__(256) void k_attn(const float* __restrict__ gpart,
                                              const float* __restrict__ normp,
                                              const float* __restrict__ temperature,
                                              float* __restrict__ att) {
    __shared__ float sA[DH][DH + 1];
    __shared__ float nrm[96];
    const int h = blockIdx.x, b = blockIdx.y;
    const int t = threadIdx.x;
    const size_t bh = b * NHEADS + h;
    if (t < 96) {
        float s = 0.f;
        for (int ck = 0; ck < 8; ++ck)
#pragma unroll
            for (int w = 0; w < 4; ++w) {
                const float* np = normp + ((bh * 8 + ck) * 4 + w) * 192 + t * 2;
                s += np[0] + np[1];
            }
        nrm[t] = fmaxf(sqrtf(s), 1e-12f);
    }
    __syncthreads();
    const float* base = gpart + (bh * 8) * (DH * DH);
    for (int e = t; e < DH * DH; e += 256) {
        float s = 0.f;
#pragma unroll
        for (int c8 = 0; c8 < 8; ++c8) s += base[(size_t)c8 * DH * DH + e];
        int c = e / DH, d = e % DH;
        sA[c][d] = s / (nrm[c] * nrm[48 + d]) * temperature[h];
    }
    __syncthreads();
    if (t < DH) {
        float m = -1e30f;
#pragma unroll
        for (int d = 0; d < DH; ++d) m = fmaxf(m, sA[t][d]);
        float s = 0.f;
        float row[DH];
#pragma unroll
        for (int d = 0; d < DH; ++d) {
            row[d] = expf(sA[t][d] - m);
            s += row[d];
        }
        float inv = 1.f / s;
#pragma unroll
        for (int d = 0; d < DH; ++d) sA[t][d] = row[d] * inv;
    }
    __syncthreads();
    float* ob = att + bh * DH * DH;
    for (int e = t; e < DH * DH; e += 256) ob[e] = sA[e / DH][e % DH];
}

// ---------------------------------------------------------------------------
// k_mw: Mw[b][o][192] = proj_w @ blockdiag(att), bf16 out. grid (6 otile, b)
// ---------------------------------------------------------------------------
__global__ __launch_bounds__(256) void k_mw(const float* __restrict__ att,
                                            const float* __restrict__ proj_w,
                                            ushort_t* __restrict__ Mw) {
    __shared__ float satt[NHEADS][DH][DH];
    __shared__ float sproj[32][CIN];
    const int o0 = blockIdx.x * 32, b = blockIdx.y;
    const int t = threadIdx.x;
    {
        const float4* src = (const float4*)(att + (size_t)b * NHEADS * DH * DH);
        float4* dst = (float4*)&satt[0][0][0];
        for (int e = t; e < NHEADS * DH * DH / 4; e += 256) dst[e] = src[e];
        const float4* ps = (const float4*)(proj_w + (size_t)o0 * CIN);
        float4* pd = (float4*)&sproj[0][0];
        for (int e = t; e < 32 * CIN / 4; e += 256) pd[e] = ps[e];
    }
    __syncthreads();
    ushort_t* ob = Mw + (size_t)b * CIN * CIN + (size_t)o0 * CIN;
    for (int e = t; e < 32 * CIN; e += 256) {
        int o = e / CIN, dg = e % CIN;
        int h = dg / DH, d = dg % DH;
        float s = 0.f;
#pragma unroll
        for (int c = 0; c < DH; ++c) s = fmaf(sproj[o][h * DH + c], satt[h][c][d], s);
        ob[e] = f2bf(s);
    }
}

// ---------------------------------------------------------------------------
// k_gemmv: out[o][pix] = sum_ch Mw[o][ch] * dw3x3(v)[ch][pix]
// dw conv fused into A-staging (reads raw pre v-planes + row halo).
// BM=128 (one image row), BN=192 (all o), 512 thr / 8 waves.
// ---------------------------------------------------------------------------
__global__ __launch_bounds__(512) void k_gemmv(const ushort_t* __restrict__ pre,
                                               const float* __restrict__ dww,
                                               const ushort_t* __restrict__ B,
                                               float* __restrict__ C) {
    __shared__ ushort_t sA[2][128 * 32];
    __shared__ ushort_t sB[2][192 * 32];
    const int t = threadIdx.x;
    const int lane = t & 63, wave = t >> 6;
    const int wrow = wave >> 1, wcol = wave & 1;
    const int Y = blockIdx.x;
    const int pix0 = Y * 128;
    const int b = blockIdx.z;
    const ushort_t* Bb = B + (size_t)b * CIN * CIN;

    const int cc = t >> 4;
    const int jj = t & 15;
    const int x0 = jj * 8;

    uint4 m[3];
    ushort_t l16[3], rg16[3];
    float wv[9];
    ushort_t av[8];

    auto loadV = [&](int kc) {
        int ch = kc + cc;
        const ushort_t* pl = pre + ((size_t)b * C3 + 2 * CIN + ch) * HWPX;
#pragma unroll
        for (int r = 0; r < 3; ++r) {
            int YY = Y - 1 + r;
            bool ok = ((unsigned)YY < 128u);
            const ushort_t* rp = pl + YY * 128;
            if (ok) {
                m[r] = *(const uint4*)(rp + x0);
                l16[r] = (x0 > 0) ? rp[x0 - 1] : (ushort_t)0;
                rg16[r] = (x0 < 120) ? rp[x0 + 8] : (ushort_t)0;
            } else {
                m[r] = make_uint4(0, 0, 0, 0);
                l16[r] = 0;
                rg16[r] = 0;
            }
        }
#pragma unroll
        for (int k = 0; k < 9; ++k) wv[k] = dww[(2 * CIN + ch) * 9 + k];
    };
    auto convV = [&]() {
        float in[3][10];
#pragma unroll
        for (int r = 0; r < 3; ++r) {
            in[r][0] = bf2f(l16[r]);
            up8(m[r], &in[r][1]);
            in[r][9] = bf2f(rg16[r]);
        }
#pragma unroll
        for (int j = 0; j < 8; ++j) {
            float o = 0.f;
#pragma unroll
            for (int ky = 0; ky < 3; ++ky) {
                o = fmaf(wv[ky * 3 + 0], in[ky][j + 0], o);
                o = fmaf(wv[ky * 3 + 1], in[ky][j + 1], o);
                o = fmaf(wv[ky * 3 + 2], in[ky][j + 2], o);
            }
            av[j] = f2bf(o);
        }
    };
    auto writeA = [&](int buf) {
        ushort_t* s = sA[buf];
#pragma unroll
        for (int i = 0; i < 8; ++i) {
            int row = jj * 8 + i;
            int slot = ((cc >> 3) + (row >> 1) + (row >> 3)) & 3;
            s[row * 32 + slot * 8 + (cc & 7)] = av[i];
        }
    };
    auto stageB = [&](int buf, int kc) {
        {
            int row = t >> 2, slot = t & 3;
            int g = (slot + (row >> 1)) & 3;
            const ushort_t* gp = Bb + (size_t)row * CIN + kc + g * 8;
            ushort_t* lp = &sB[buf][(wave * 64) * 8];
            ASYNC_COPY16(gp, lp);
        }
        if (t < 256) {
            int e = 512 + t;
            int row = e >> 2, slot = e & 3;
            int g = (slot + (row >> 1)) & 3;
            const ushort_t* gp = Bb + (size_t)row * CIN + kc + g * 8;
            ushort_t* lp = &sB[buf][(512 + wave * 64) * 8];
            ASYNC_COPY16(gp, lp);
        }
    };

    f32x4 acc[2][6];
#pragma unroll
    for (int mi = 0; mi < 2; ++mi)
#pragma unroll
        for (int ni = 0; ni < 6; ++ni) acc[mi][ni] = (f32x4){0.f, 0.f, 0.f, 0.f};

    loadV(0);
    convV();
    writeA(0);
    stageB(0, 0);
#pragma unroll
    for (int ks = 0; ks < 6; ++ks) {
        __syncthreads();
        const int buf = ks & 1;
        if (ks < 5) {
            loadV((ks + 1) * 32);
            stageB(buf ^ 1, (ks + 1) * 32);
        }
        const ushort_t* a_ = sA[buf];
        const ushort_t* b_ = sB[buf];
        const int c = lane >> 4;
        bf16x8 af[2], bfr[6];
#pragma unroll
        for (int mi = 0; mi < 2; ++mi) {
            int row = wrow * 32 + mi * 16 + (lane & 15);
            int slot = (c + (row >> 1) + (row >> 3)) & 3;
            af[mi] = *(const bf16x8*)&a_[row * 32 + slot * 8];
        }
#pragma unroll
        for (int ni = 0; ni < 6; ++ni) {
            int row = wcol * 96 + ni * 16 + (lane & 15);
            int slot = (c - (row >> 1)) & 3;
            bfr[ni] = *(const bf16x8*)&b_[row * 32 + slot * 8];
        }
#pragma unroll
        for (int mi = 0; mi < 2; ++mi)
#pragma unroll
            for (int ni = 0; ni < 6; ++ni)
                acc[mi][ni] = __builtin_amdgcn_mfma_f32_16x16x32_bf16(
                    af[mi], bfr[ni], acc[mi][ni], 0, 0, 0);
        if (ks < 5) {
            convV();
            writeA(buf ^ 1);
        }
    }

    const int ocol = lane & 15;
    const int prow = (lane >> 4) * 4;
#pragma unroll
    for (int mi = 0; mi < 2; ++mi) {
        int pix = pix0 + wrow * 32 + mi * 16 + prow;
#pragma unroll
        for (int ni = 0; ni < 6; ++ni) {
            int o = wcol * 96 + ni * 16 + ocol;
            f32x4 v = acc[mi][ni];
            float* Cp = C + ((size_t)b * CIN + o) * HWPX + pix;
            *(float4*)Cp = make_float4(v[0], v[1], v[2], v[3]);
        }
    }
}

extern "C" void kernel_launch(void* const* d_in, const int* in_sizes, int n_in,
                              void* d_out, int out_size, void* d_ws, size_t ws_size,
                              hipStream_t stream) {
    const float* x = (const float*)d_in[0];
    const float* qkv_w = (const float*)d_in[1];
    const float* dw_w = (const float*)d_in[2];
    const float* proj_w = (const float*)d_in[3];
    const float* temperature = (const float*)d_in[4];
    float* out = (float*)d_out;

    char* ws = (char*)d_ws;
    ushort_t* pre = (ushort_t*)ws;
    float* normp = (float*)(ws + 150994944);
    float* gpart = (float*)(ws + 151781376);
    ushort_t* Mw = (ushort_t*)(ws + 154140672);
    float* attb = (float*)(ws + 154730496);
    ushort_t* wq = (ushort_t*)(ws + 155025408);

    k_cvtw<<<dim3(108), 256, 0, stream>>>(qkv_w, wq);
    k_gemm<<<dim3(128, 1, 8), 512, 0, stream>>>(x, wq, pre);
    k_gramdw<<<dim3(8, NHEADS, 8), 256, 0, stream>>>(pre, dw_w, gpart, normp);
    k_attn<<<dim3(NHEADS, 8), 256, 0, stream>>>(gpart, normp, temperature, attb);
    k_mw<<<dim3(6, 8), 256, 0, stream>>>(attb, proj_w, Mw);
    k_gemmv<<<dim3(128, 1, 8), 512, 0, stream>>>(pre, dw_w, Mw, out);
}

// Round 12
// 211.192 us; speedup vs baseline: 1.4729x; 1.0070x over previous
//
#include <hip/hip_runtime.h>
#include <hip/hip_bf16.h>

#define CIN 192
#define C3 576
#define HWPX 16384
#define NHEADS 4
#define DH 48

typedef unsigned short ushort_t;
typedef __attribute__((ext_vector_type(8))) short bf16x8;
typedef __attribute__((ext_vector_type(4))) float f32x4;

__device__ __forceinline__ float bf2f(unsigned short u) {
    return __uint_as_float(((unsigned int)u) << 16);
}
__device__ __forceinline__ unsigned short f2bf(float f) {
    unsigned int u = __float_as_uint(f);
    unsigned int r = (u >> 16) & 1u;
    u += 0x7fffu + r;
    return (unsigned short)(u >> 16);
}
__device__ __forceinline__ void up8(uint4 a, float* o) {
    o[0] = __uint_as_float(a.x << 16); o[1] = __uint_as_float(a.x & 0xffff0000u);
    o[2] = __uint_as_float(a.y << 16); o[3] = __uint_as_float(a.y & 0xffff0000u);
    o[4] = __uint_as_float(a.z << 16); o[5] = __uint_as_float(a.z & 0xffff0000u);
    o[6] = __uint_as_float(a.w << 16); o[7] = __uint_as_float(a.w & 0xffff0000u);
}

// ---------------------------------------------------------------------------
// k_cvtw: qkv_w fp32 [576,192] -> bf16 PACKED in MFMA fragment order.
// Fragment (og,ks,ni16) is a 1KB block: lane (c*16+r) holds
// B[og*192+ni16*16+r][ks*32+c*8 .. +8].
// ---------------------------------------------------------------------------
__global__ __launch_bounds__(256) void k_cvtw(const float* __restrict__ w,
                                              ushort_t* __restrict__ wb) {
    int i = (blockIdx.x * 256 + threadIdx.x) * 4;
    float4 v = *(const float4*)(w + i);
    int row = i / CIN, k = i % CIN;
    int og = row / 192, rowin = row % 192;
    int ni16 = rowin >> 4, r = rowin & 15;
    int ks = k >> 5, c = (k >> 3) & 3, e8 = k & 7;
    size_t idx = ((((size_t)(og * 6 + ks)) * 12 + ni16) * 64 + (c * 16 + r)) * 8 + e8;
    uint2 pk;
    pk.x = (unsigned)f2bf(v.x) | ((unsigned)f2bf(v.y) << 16);
    pk.y = (unsigned)f2bf(v.z) | ((unsigned)f2bf(v.w) << 16);
    *(uint2*)(wb + idx) = pk;
}

// ---------------------------------------------------------------------------
// k_gemm: pre[o][pix] = sum_k x[k][pix] * wq[o][k]   (MFMA bf16)
// Full-K A (128px x 192K, 48KB LDS) staged ONCE; ONE barrier; then 3 o-groups
// x 6 K-steps of {2 A ds_reads + 6 direct global B-frag loads + 12 MFMA},
// NO further barriers. B pre-packed in fragment order (k_cvtw).
// ---------------------------------------------------------------------------
__global__ __launch_bounds__(512) void k_gemm(const float* __restrict__ A,
                                              const ushort_t* __restrict__ B,
                                              ushort_t* __restrict__ C) {
    __shared__ ushort_t sA[6 * 128 * 32];  // 48 KB
    const int t = threadIdx.x;
    const int lane = t & 63, wave = t >> 6;
    const int wrow = wave >> 1, wcol = wave & 1;
    const int pix0 = blockIdx.x * 128;
    const int b = blockIdx.z;
    const int cc = t >> 4;  // channel-in-chunk 0..31
    const int jj = t & 15;  // pixel phase 0..15

    // ---- stage full-K A once ----
    {
        float avf[6][8];
#pragma unroll
        for (int c6 = 0; c6 < 6; ++c6) {
            const float* Ab = A + (size_t)b * CIN * HWPX +
                              (size_t)(c6 * 32 + cc) * HWPX + pix0 + jj;
#pragma unroll
            for (int i = 0; i < 8; ++i) avf[c6][i] = Ab[16 * i];
        }
#pragma unroll
        for (int c6 = 0; c6 < 6; ++c6) {
            ushort_t* s = &sA[c6 * 4096];
#pragma unroll
            for (int i = 0; i < 8; ++i) {
                int row = jj + 16 * i;
                int slot = ((cc >> 3) + (row >> 1) + (row >> 3)) & 3;
                s[row * 32 + slot * 8 + (cc & 7)] = f2bf(avf[c6][i]);
            }
        }
    }
    __syncthreads();  // the ONLY barrier

    const int c = lane >> 4;
    const int ocol = lane & 15;
    const int prow = (lane >> 4) * 4;

    f32x4 acc[2][6];
#pragma unroll
    for (int mi = 0; mi < 2; ++mi)
#pragma unroll
        for (int ni = 0; ni < 6; ++ni) acc[mi][ni] = (f32x4){0.f, 0.f, 0.f, 0.f};

#pragma unroll
    for (int og = 0; og < 3; ++og) {
#pragma unroll
        for (int ks = 0; ks < 6; ++ks) {
            const ushort_t* a_ = &sA[ks * 4096];
            bf16x8 af[2], bfr[6];
#pragma unroll
            for (int mi = 0; mi < 2; ++mi) {
                int row = wrow * 32 + mi * 16 + (lane & 15);
                int slot = (c + (row >> 1) + (row >> 3)) & 3;
                af[mi] = *(const bf16x8*)&a_[row * 32 + slot * 8];
            }
#pragma unroll
            for (int ni = 0; ni < 6; ++ni) {
                size_t fidx = ((((size_t)(og * 6 + ks)) * 12 + wcol * 6 + ni) * 64 + lane) * 8;
                bfr[ni] = *(const bf16x8*)&B[fidx];
            }
#pragma unroll
            for (int mi = 0; mi < 2; ++mi)
#pragma unroll
                for (int ni = 0; ni < 6; ++ni)
                    acc[mi][ni] = __builtin_amdgcn_mfma_f32_16x16x32_bf16(
                        af[mi], bfr[ni], acc[mi][ni], 0, 0, 0);
        }
#pragma unroll
        for (int mi = 0; mi < 2; ++mi) {
            int pix = pix0 + wrow * 32 + mi * 16 + prow;
#pragma unroll
            for (int ni = 0; ni < 6; ++ni) {
                int o = og * 192 + wcol * 96 + ni * 16 + ocol;
                f32x4 v = acc[mi][ni];
                ushort_t* Cp = C + ((size_t)b * C3 + o) * HWPX + pix;
                uint2 pk;
                pk.x = (unsigned)f2bf(v[0]) | ((unsigned)f2bf(v[1]) << 16);
                pk.y = (unsigned)f2bf(v[2]) | ((unsigned)f2bf(v[3]) << 16);
                *(uint2*)Cp = pk;
                acc[mi][ni] = (f32x4){0.f, 0.f, 0.f, 0.f};
            }
        }
    }
}

// ---------------------------------------------------------------------------
// k_gramdw: fused {3x3 dw conv on q,k} + {gram partials} + {ssq partials}
// (unchanged from round 11)
// ---------------------------------------------------------------------------
__global__ __launch_bounds__(256, 1) void k_gramdw(const ushort_t* __restrict__ pre,
                                                   const float* __restrict__ dww,
                                                   float* __restrict__ gpart,
                                                   float* __restrict__ normp) {
    __shared__ char smem[NHEADS * DH * DH * 4];
    ushort_t* sCw = (ushort_t*)smem + (threadIdx.x >> 6) * (96 * 40);
    float* sG = (float*)smem;

    const int chunk = blockIdx.x, h = blockIdx.y, b = blockIdx.z;
    const int t = threadIdx.x;
    const int lane = t & 63, wave = t >> 6;
    const int y0 = chunk * 16;

    const ushort_t* plane[3];
    float wreg[3][9];
    int pxb[3];
#pragma unroll
    for (int u = 0; u < 3; ++u) {
        int id = lane + 64 * u;
        int c96 = id >> 1;
        int gch = (c96 < DH) ? (h * DH + c96) : (CIN + h * DH + (c96 - DH));
        plane[u] = pre + ((size_t)b * C3 + gch) * HWPX;
        pxb[u] = wave * 32 + (id & 1) * 16;
#pragma unroll
        for (int k = 0; k < 9; ++k) wreg[u][k] = dww[gch * 9 + k];
    }

    float ssq[3] = {0.f, 0.f, 0.f};
    f32x4 acc[3][3];
#pragma unroll
    for (int i = 0; i < 3; ++i)
#pragma unroll
        for (int j = 0; j < 3; ++j) acc[i][j] = (f32x4){0.f, 0.f, 0.f, 0.f};

    uint4 ring[3][3][2];
    ushort_t lfr[3][3], rgr[3][3];
    uint4 nx[3][2];
    ushort_t nlf[3], nrg[3];

    auto LOADROW = [&](int YY) {
#pragma unroll
        for (int u = 0; u < 3; ++u) {
            bool ok = ((unsigned)YY < 128u);
            const ushort_t* rp = plane[u] + YY * 128 + pxb[u];
            if (ok) {
                nx[u][0] = *(const uint4*)rp;
                nx[u][1] = *(const uint4*)(rp + 8);
                nlf[u] = (pxb[u] > 0) ? rp[-1] : (ushort_t)0;
                nrg[u] = (pxb[u] + 16 < 128) ? rp[16] : (ushort_t)0;
            } else {
                nx[u][0] = make_uint4(0, 0, 0, 0);
                nx[u][1] = make_uint4(0, 0, 0, 0);
                nlf[u] = 0;
                nrg[u] = 0;
            }
        }
    };
    auto PUT = [&](int rp) {
#pragma unroll
        for (int u = 0; u < 3; ++u) {
            ring[rp][u][0] = nx[u][0];
            ring[rp][u][1] = nx[u][1];
            lfr[rp][u] = nlf[u];
            rgr[rp][u] = nrg[u];
        }
    };

    LOADROW(y0 - 1); PUT(0);
    LOADROW(y0);     PUT(1);
    LOADROW(y0 + 1); PUT(2);

    for (int s = 0; s < 16; ++s) {
        if (s < 15) LOADROW(y0 + s + 2);
#pragma unroll
        for (int u = 0; u < 3; ++u) {
            int id = lane + 64 * u;
            float in[3][18];
#pragma unroll
            for (int r = 0; r < 3; ++r) {
                in[r][0] = bf2f(lfr[r][u]);
                up8(ring[r][u][0], &in[r][1]);
                up8(ring[r][u][1], &in[r][9]);
                in[r][17] = bf2f(rgr[r][u]);
            }
            unsigned pk[8];
#pragma unroll
            for (int j2 = 0; j2 < 8; ++j2) {
                float o0 = 0.f, o1 = 0.f;
#pragma unroll
                for (int ky = 0; ky < 3; ++ky) {
                    o0 = fmaf(wreg[u][ky * 3 + 0], in[ky][2 * j2 + 0], o0);
                    o0 = fmaf(wreg[u][ky * 3 + 1], in[ky][2 * j2 + 1], o0);
                    o0 = fmaf(wreg[u][ky * 3 + 2], in[ky][2 * j2 + 2], o0);
                    o1 = fmaf(wreg[u][ky * 3 + 0], in[ky][2 * j2 + 1], o1);
                    o1 = fmaf(wreg[u][ky * 3 + 1], in[ky][2 * j2 + 2], o1);
                    o1 = fmaf(wreg[u][ky * 3 + 2], in[ky][2 * j2 + 3], o1);
                }
                ssq[u] = fmaf(o0, o0, ssq[u]);
                ssq[u] = fmaf(o1, o1, ssq[u]);
                pk[j2] = (unsigned)f2bf(o0) | ((unsigned)f2bf(o1) << 16);
            }
            uint4* dst = (uint4*)&sCw[(id >> 1) * 40 + ((id & 1) << 4)];
            dst[0] = make_uint4(pk[0], pk[1], pk[2], pk[3]);
            dst[1] = make_uint4(pk[4], pk[5], pk[6], pk[7]);
        }
        {
            bf16x8 af[3], bk[3];
#pragma unroll
            for (int i = 0; i < 3; ++i)
                af[i] = *(const bf16x8*)&sCw[(i * 16 + (lane & 15)) * 40 + (lane >> 4) * 8];
#pragma unroll
            for (int j = 0; j < 3; ++j)
                bk[j] = *(const bf16x8*)&sCw[(48 + j * 16 + (lane & 15)) * 40 + (lane >> 4) * 8];
#pragma unroll
            for (int i = 0; i < 3; ++i)
#pragma unroll
                for (int j = 0; j < 3; ++j)
                    acc[i][j] = __builtin_amdgcn_mfma_f32_16x16x32_bf16(af[i], bk[j],
                                                                        acc[i][j], 0, 0, 0);
        }
        if (s < 15) {
#pragma unroll
            for (int u = 0; u < 3; ++u) {
                ring[0][u][0] = ring[1][u][0]; ring[0][u][1] = ring[1][u][1];
                ring[1][u][0] = ring[2][u][0]; ring[1][u][1] = ring[2][u][1];
                ring[2][u][0] = nx[u][0];      ring[2][u][1] = nx[u][1];
                lfr[0][u] = lfr[1][u]; lfr[1][u] = lfr[2][u]; lfr[2][u] = nlf[u];
                rgr[0][u] = rgr[1][u]; rgr[1][u] = rgr[2][u]; rgr[2][u] = nrg[u];
            }
        }
    }

    __syncthreads();
    const int crow = (lane >> 4) * 4;
    const int dcol = lane & 15;
#pragma unroll
    for (int i = 0; i < 3; ++i)
#pragma unroll
        for (int j = 0; j < 3; ++j)
#pragma unroll
            for (int r = 0; r < 4; ++r)
                sG[(size_t)wave * DH * DH + (i * 16 + crow + r) * DH + j * 16 + dcol] =
                    acc[i][j][r];
    __syncthreads();
    float* g = gpart + (((size_t)(b * NHEADS + h)) * 8 + chunk) * (DH * DH);
    for (int e = t; e < DH * DH; e += 256)
        g[e] = sG[e] + sG[DH * DH + e] + sG[2 * DH * DH + e] + sG[3 * DH * DH + e];

    float* np = normp + ((((size_t)(b * NHEADS + h)) * 8 + chunk) * 4 + wave) * 192;
#pragma unroll
    for (int u = 0; u < 3; ++u) np[lane + 64 * u] = ssq[u];
}

// ---------------------------------------------------------------------------
// k_attn: sum gram+norm partials -> normalize -> softmax -> att fp32
// ---------------------------------------------------------------------------
__global__ __launch_bounds__(256) void k_attn(const float* __restrict__ gpart,
                                              const float* __restrict__ normp,
                                              const float* __restrict__ temperature,
                                              float* __restrict__ att) {
    __shared__ float sA[DH][DH + 1];
    __shared__ float nrm[96];
    const int h = blockIdx.x, b = blockIdx.y;
    const int t = threadIdx.x;
    const size_t bh = b * NHEADS + h;
    if (t < 96) {
        float s = 0.f;
        for (int ck = 0; ck < 8; ++ck)
#pragma unroll
            for (int w = 0; w < 4; ++w) {
                const float* np = normp + ((bh * 8 + ck) * 4 + w) * 192 + t * 2;
                s += np[0] + np[1];
            }
        nrm[t] = fmaxf(sqrtf(s), 1e-12f);
    }
    __syncthreads();
    const float* base = gpart + (bh * 8) * (DH * DH);
    for (int e = t; e < DH * DH; e += 256) {
        float s = 0.f;
#pragma unroll
        for (int c8 = 0; c8 < 8; ++c8) s += base[(size_t)c8 * DH * DH + e];
        int c = e / DH, d = e % DH;
        sA[c][d] = s / (nrm[c] * nrm[48 + d]) * temperature[h];
    }
    __syncthreads();
    if (t < DH) {
        float m = -1e30f;
#pragma unroll
        for (int d = 0; d < DH; ++d) m = fmaxf(m, sA[t][d]);
        float s = 0.f;
        float row[DH];
#pragma unroll
        for (int d = 0; d < DH; ++d) {
            row[d] = expf(sA[t][d] - m);
            s += row[d];
        }
        float inv = 1.f / s;
#pragma unroll
        for (int d = 0; d < DH; ++d) sA[t][d] = row[d] * inv;
    }
    __syncthreads();
    float* ob = att + bh * DH * DH;
    for (int e = t; e < DH * DH; e += 256) ob[e] = sA[e / DH][e % DH];
}

// ---------------------------------------------------------------------------
// k_mw: Mw = proj_w @ blockdiag(att), bf16, written PACKED in fragment order:
// frag (ks,ni16) 1KB block, lane (c*16+r) holds Mw[ni16*16+r][ks*32+c*8..+8].
// ---------------------------------------------------------------------------
__global__ __launch_bounds__(256) void k_mw(const float* __restrict__ att,
                                            const float* __restrict__ proj_w,
                                            ushort_t* __restrict__ Mw) {
    __shared__ float satt[NHEADS][DH][DH];
    __shared__ float sproj[32][CIN];
    const int o0 = blockIdx.x * 32, b = blockIdx.y;
    const int t = threadIdx.x;
    {
        const float4* src = (const float4*)(att + (size_t)b * NHEADS * DH * DH);
        float4* dst = (float4*)&satt[0][0][0];
        for (int e = t; e < NHEADS * DH * DH / 4; e += 256) dst[e] = src[e];
        const float4* ps = (const float4*)(proj_w + (size_t)o0 * CIN);
        float4* pd = (float4*)&sproj[0][0];
        for (int e = t; e < 32 * CIN / 4; e += 256) pd[e] = ps[e];
    }
    __syncthreads();
    ushort_t* ob = Mw + (size_t)b * CIN * CIN;
    for (int e = t; e < 32 * CIN; e += 256) {
        int o = e / CIN, dg = e % CIN;
        int h = dg / DH, d = dg % DH;
        float s = 0.f;
#pragma unroll
        for (int c = 0; c < DH; ++c) s = fmaf(sproj[o][h * DH + c], satt[h][c][d], s);
        int row = o0 + o;
        int ni16 = row >> 4, r = row & 15;
        int ks = dg >> 5, cq = (dg >> 3) & 3, e8 = dg & 7;
        size_t idx = (((size_t)ks * 12 + ni16) * 64 + (cq * 16 + r)) * 8 + e8;
        ob[idx] = f2bf(s);
    }
}

// ---------------------------------------------------------------------------
// k_gemmv: out[o][pix] = sum_ch Mw[o][ch] * dw3x3(v)[ch][pix]
// Conv'd full-K A (128px x 192ch, 48KB) staged ONCE; ONE barrier; then
// 6 K-steps of {2 A ds_reads + 6 direct packed-Mw frag loads + 12 MFMA}.
// ---------------------------------------------------------------------------
__global__ __launch_bounds__(512) void k_gemmv(const ushort_t* __restrict__ pre,
                                               const float* __restrict__ dww,
                                               const ushort_t* __restrict__ Bp,
                                               float* __restrict__ C) {
    __shared__ ushort_t sA[6 * 128 * 32];  // 48 KB
    const int t = threadIdx.x;
    const int lane = t & 63, wave = t >> 6;
    const int wrow = wave >> 1, wcol = wave & 1;
    const int Y = blockIdx.x;
    const int pix0 = Y * 128;
    const int b = blockIdx.z;
    const ushort_t* Bb = Bp + (size_t)b * CIN * CIN;

    const int cc = t >> 4;
    const int jj = t & 15;
    const int x0 = jj * 8;

    // ---- stage conv'd full-K A once ----
#pragma unroll
    for (int c6 = 0; c6 < 6; ++c6) {
        int ch = c6 * 32 + cc;
        const ushort_t* pl = pre + ((size_t)b * C3 + 2 * CIN + ch) * HWPX;
        uint4 m[3];
        ushort_t l16[3], rg16[3];
#pragma unroll
        for (int r = 0; r < 3; ++r) {
            int YY = Y - 1 + r;
            bool ok = ((unsigned)YY < 128u);
            const ushort_t* rp = pl + YY * 128;
            if (ok) {
                m[r] = *(const uint4*)(rp + x0);
                l16[r] = (x0 > 0) ? rp[x0 - 1] : (ushort_t)0;
                rg16[r] = (x0 < 120) ? rp[x0 + 8] : (ushort_t)0;
            } else {
                m[r] = make_uint4(0, 0, 0, 0);
                l16[r] = 0;
                rg16[r] = 0;
            }
        }
        float wv[9];
#pragma unroll
        for (int k = 0; k < 9; ++k) wv[k] = dww[(2 * CIN + ch) * 9 + k];
        float in[3][10];
#pragma unroll
        for (int r = 0; r < 3; ++r) {
            in[r][0] = bf2f(l16[r]);
            up8(m[r], &in[r][1]);
            in[r][9] = bf2f(rg16[r]);
        }
        ushort_t* s = &sA[c6 * 4096];
#pragma unroll
        for (int j = 0; j < 8; ++j) {
            float o = 0.f;
#pragma unroll
            for (int ky = 0; ky < 3; ++ky) {
                o = fmaf(wv[ky * 3 + 0], in[ky][j + 0], o);
                o = fmaf(wv[ky * 3 + 1], in[ky][j + 1], o);
                o = fmaf(wv[ky * 3 + 2], in[ky][j + 2], o);
            }
            int row = jj * 8 + j;
            int slot = ((cc >> 3) + (row >> 1) + (row >> 3)) & 3;
            s[row * 32 + slot * 8 + (cc & 7)] = f2bf(o);
        }
    }
    __syncthreads();  // the ONLY barrier

    const int c = lane >> 4;
    f32x4 acc[2][6];
#pragma unroll
    for (int mi = 0; mi < 2; ++mi)
#pragma unroll
        for (int ni = 0; ni < 6; ++ni) acc[mi][ni] = (f32x4){0.f, 0.f, 0.f, 0.f};

#pragma unroll
    for (int ks = 0; ks < 6; ++ks) {
        const ushort_t* a_ = &sA[ks * 4096];
        bf16x8 af[2], bfr[6];
#pragma unroll
        for (int mi = 0; mi < 2; ++mi) {
            int row = wrow * 32 + mi * 16 + (lane & 15);
            int slot = (c + (row >> 1) + (row >> 3)) & 3;
            af[mi] = *(const bf16x8*)&a_[row * 32 + slot * 8];
        }
#pragma unroll
        for (int ni = 0; ni < 6; ++ni) {
            size_t fidx = (((size_t)ks * 12 + wcol * 6 + ni) * 64 + lane) * 8;
            bfr[ni] = *(const bf16x8*)&Bb[fidx];
        }
#pragma unroll
        for (int mi = 0; mi < 2; ++mi)
#pragma unroll
            for (int ni = 0; ni < 6; ++ni)
                acc[mi][ni] = __builtin_amdgcn_mfma_f32_16x16x32_bf16(
                    af[mi], bfr[ni], acc[mi][ni], 0, 0, 0);
    }

    const int ocol = lane & 15;
    const int prow = (lane >> 4) * 4;
#pragma unroll
    for (int mi = 0; mi < 2; ++mi) {
        int pix = pix0 + wrow * 32 + mi * 16 + prow;
#pragma unroll
        for (int ni = 0; ni < 6; ++ni) {
            int o = wcol * 96 + ni * 16 + ocol;
            f32x4 v = acc[mi][ni];
            float* Cp = C + ((size_t)b * CIN + o) * HWPX + pix;
            *(float4*)Cp = make_float4(v[0], v[1], v[2], v[3]);
        }
    }
}

extern "C" void kernel_launch(void* const* d_in, const int* in_sizes, int n_in,
                              void* d_out, int out_size, void* d_ws, size_t ws_size,
                              hipStream_t stream) {
    const float* x = (const float*)d_in[0];
    const float* qkv_w = (const float*)d_in[1];
    const float* dw_w = (const float*)d_in[2];
    const float* proj_w = (const float*)d_in[3];
    const float* temperature = (const float*)d_in[4];
    float* out = (float*)d_out;

    char* ws = (char*)d_ws;
    ushort_t* pre = (ushort_t*)ws;
    float* normp = (float*)(ws + 150994944);
    float* gpart = (float*)(ws + 151781376);
    ushort_t* Mw = (ushort_t*)(ws + 154140672);
    float* attb = (float*)(ws + 154730496);
    ushort_t* wq = (ushort_t*)(ws + 155025408);

    k_cvtw<<<dim3(108), 256, 0, stream>>>(qkv_w, wq);
    k_gemm<<<dim3(128, 1, 8), 512, 0, stream>>>(x, wq, pre);
    k_gramdw<<<dim3(8, NHEADS, 8), 256, 0, stream>>>(pre, dw_w, gpart, normp);
    k_attn<<<dim3(NHEADS, 8), 256, 0, stream>>>(gpart, normp, temperature, attb);
    k_mw<<<dim3(6, 8), 256, 0, stream>>>(attb, proj_w, Mw);
    k_gemmv<<<dim3(128, 1, 8), 512, 0, stream>>>(pre, dw_w, Mw, out);
}

// Round 13
// 201.671 us; speedup vs baseline: 1.5425x; 1.0472x over previous
//
#include <hip/hip_runtime.h>
#include <hip/hip_bf16.h>

#define CIN 192
#define C3 576
#define HWPX 16384
#define NHEADS 4
#define DH 48

typedef unsigned short ushort_t;
typedef __attribute__((ext_vector_type(8))) short bf16x8;
typedef __attribute__((ext_vector_type(4))) float f32x4;

__device__ __forceinline__ float bf2f(unsigned short u) {
    return __uint_as_float(((unsigned int)u) << 16);
}
__device__ __forceinline__ unsigned short f2bf(float f) {
    unsigned int u = __float_as_uint(f);
    unsigned int r = (u >> 16) & 1u;
    u += 0x7fffu + r;
    return (unsigned short)(u >> 16);
}
__device__ __forceinline__ void up8(uint4 a, float* o) {
    o[0] = __uint_as_float(a.x << 16); o[1] = __uint_as_float(a.x & 0xffff0000u);
    o[2] = __uint_as_float(a.y << 16); o[3] = __uint_as_float(a.y & 0xffff0000u);
    o[4] = __uint_as_float(a.z << 16); o[5] = __uint_as_float(a.z & 0xffff0000u);
    o[6] = __uint_as_float(a.w << 16); o[7] = __uint_as_float(a.w & 0xffff0000u);
}

#define ASYNC_COPY16(gptr, lptr)                                                   \
    __builtin_amdgcn_global_load_lds(                                              \
        (__attribute__((address_space(1))) void*)(gptr),                           \
        (__attribute__((address_space(3))) void*)(lptr), 16, 0, 0)

// ---------------------------------------------------------------------------
// k_cvtw: qkv_w fp32 [576,192] -> bf16 row-major (consumed by k_gemm stageB)
// ---------------------------------------------------------------------------
__global__ __launch_bounds__(256) void k_cvtw(const float* __restrict__ w,
                                              ushort_t* __restrict__ wb) {
    int i = (blockIdx.x * 256 + threadIdx.x) * 4;
    float4 v = *(const float4*)(w + i);
    uint2 pk;
    pk.x = (unsigned)f2bf(v.x) | ((unsigned)f2bf(v.y) << 16);
    pk.y = (unsigned)f2bf(v.z) | ((unsigned)f2bf(v.w) << 16);
    *(uint2*)(wb + i) = pk;
}

// ---------------------------------------------------------------------------
// k_gemm: pre[o][pix] = sum_k x[k][pix] * wq[o][k]   (MFMA bf16)
// Full-K A tile (128px x 192K, 48KB) staged ONCE per block; then 3 o-group
// passes x 6 K-steps each {dbuf LDS stageB, 12 MFMA/wave} reuse it.
// 512 thr / 8 waves (4x2), wave = 32px x 96o (2x6 frags).  [round-11 best]
// ---------------------------------------------------------------------------
__global__ __launch_bounds__(512) void k_gemm(const float* __restrict__ A,
                                              const ushort_t* __restrict__ B,
                                              ushort_t* __restrict__ C) {
    __shared__ ushort_t sA[6 * 128 * 32];     // 48 KB, chunk c at c*4096
    __shared__ ushort_t sB[2][192 * 32];      // 24 KB
    const int t = threadIdx.x;
    const int lane = t & 63, wave = t >> 6;
    const int wrow = wave >> 1, wcol = wave & 1;
    const int pix0 = blockIdx.x * 128;
    const int b = blockIdx.z;

    const int cc = t >> 4;  // channel-in-chunk 0..31
    const int jj = t & 15;  // pixel phase 0..15

    // ---- stage full-K A once ----
    {
        float avf[6][8];
#pragma unroll
        for (int c6 = 0; c6 < 6; ++c6) {
            const float* Ab = A + (size_t)b * CIN * HWPX +
                              (size_t)(c6 * 32 + cc) * HWPX + pix0 + jj;
#pragma unroll
            for (int i = 0; i < 8; ++i) avf[c6][i] = Ab[16 * i];
        }
#pragma unroll
        for (int c6 = 0; c6 < 6; ++c6) {
            ushort_t* s = &sA[c6 * 4096];
#pragma unroll
            for (int i = 0; i < 8; ++i) {
                int row = jj + 16 * i;
                int slot = ((cc >> 3) + (row >> 1) + (row >> 3)) & 3;
                s[row * 32 + slot * 8 + (cc & 7)] = f2bf(avf[c6][i]);
            }
        }
    }

    auto stageB = [&](int buf, int og, int kc) {
        const ushort_t* Bb = B + (size_t)og * 192 * CIN;
        {
            int row = t >> 2, slot = t & 3;
            int g = (slot + (row >> 1)) & 3;
            const ushort_t* gp = Bb + (size_t)row * CIN + kc + g * 8;
            ushort_t* lp = &sB[buf][(wave * 64) * 8];
            ASYNC_COPY16(gp, lp);
        }
        if (t < 256) {
            int e = 512 + t;
            int row = e >> 2, slot = e & 3;
            int g = (slot + (row >> 1)) & 3;
            const ushort_t* gp = Bb + (size_t)row * CIN + kc + g * 8;
            ushort_t* lp = &sB[buf][(512 + wave * 64) * 8];
            ASYNC_COPY16(gp, lp);
        }
    };

    f32x4 acc[2][6];
#pragma unroll
    for (int mi = 0; mi < 2; ++mi)
#pragma unroll
        for (int ni = 0; ni < 6; ++ni) acc[mi][ni] = (f32x4){0.f, 0.f, 0.f, 0.f};

    stageB(0, 0, 0);

    const int ocol = lane & 15;
    const int prow = (lane >> 4) * 4;
    const int c = lane >> 4;

#pragma unroll
    for (int og = 0; og < 3; ++og) {
#pragma unroll
        for (int ks = 0; ks < 6; ++ks) {
            const int step = og * 6 + ks;
            const int buf = step & 1;
            __syncthreads();
            if (step + 1 < 18)
                stageB(buf ^ 1, (step + 1) / 6, ((step + 1) % 6) * 32);
            const ushort_t* a_ = &sA[ks * 4096];
            const ushort_t* b_ = sB[buf];
            bf16x8 af[2], bfr[6];
#pragma unroll
            for (int mi = 0; mi < 2; ++mi) {
                int row = wrow * 32 + mi * 16 + (lane & 15);
                int slot = (c + (row >> 1) + (row >> 3)) & 3;
                af[mi] = *(const bf16x8*)&a_[row * 32 + slot * 8];
            }
#pragma unroll
            for (int ni = 0; ni < 6; ++ni) {
                int row = wcol * 96 + ni * 16 + (lane & 15);
                int slot = (c - (row >> 1)) & 3;
                bfr[ni] = *(const bf16x8*)&b_[row * 32 + slot * 8];
            }
#pragma unroll
            for (int mi = 0; mi < 2; ++mi)
#pragma unroll
                for (int ni = 0; ni < 6; ++ni)
                    acc[mi][ni] = __builtin_amdgcn_mfma_f32_16x16x32_bf16(
                        af[mi], bfr[ni], acc[mi][ni], 0, 0, 0);
        }
        // epilogue for this o-group
#pragma unroll
        for (int mi = 0; mi < 2; ++mi) {
            int pix = pix0 + wrow * 32 + mi * 16 + prow;
#pragma unroll
            for (int ni = 0; ni < 6; ++ni) {
                int o = og * 192 + wcol * 96 + ni * 16 + ocol;
                f32x4 v = acc[mi][ni];
                ushort_t* Cp = C + ((size_t)b * C3 + o) * HWPX + pix;
                uint2 pk;
                pk.x = (unsigned)f2bf(v[0]) | ((unsigned)f2bf(v[1]) << 16);
                pk.y = (unsigned)f2bf(v[2]) | ((unsigned)f2bf(v[3]) << 16);
                *(uint2*)Cp = pk;
                acc[mi][ni] = (f32x4){0.f, 0.f, 0.f, 0.f};
            }
        }
    }
}

// ---------------------------------------------------------------------------
// k_gramdw: fused {3x3 dw conv on q,k} + {gram partials} + {ssq partials}
// ---------------------------------------------------------------------------
__global__ __launch_bounds__(256, 1) void k_gramdw(const ushort_t* __restrict__ pre,
                                                   const float* __restrict__ dww,
                                                   float* __restrict__ gpart,
                                                   float* __restrict__ normp) {
    __shared__ char smem[NHEADS * DH * DH * 4];
    ushort_t* sCw = (ushort_t*)smem + (threadIdx.x >> 6) * (96 * 40);
    float* sG = (float*)smem;

    const int chunk = blockIdx.x, h = blockIdx.y, b = blockIdx.z;
    const int t = threadIdx.x;
    const int lane = t & 63, wave = t >> 6;
    const int y0 = chunk * 16;

    const ushort_t* plane[3];
    float wreg[3][9];
    int pxb[3];
#pragma unroll
    for (int u = 0; u < 3; ++u) {
        int id = lane + 64 * u;
        int c96 = id >> 1;
        int gch = (c96 < DH) ? (h * DH + c96) : (CIN + h * DH + (c96 - DH));
        plane[u] = pre + ((size_t)b * C3 + gch) * HWPX;
        pxb[u] = wave * 32 + (id & 1) * 16;
#pragma unroll
        for (int k = 0; k < 9; ++k) wreg[u][k] = dww[gch * 9 + k];
    }

    float ssq[3] = {0.f, 0.f, 0.f};
    f32x4 acc[3][3];
#pragma unroll
    for (int i = 0; i < 3; ++i)
#pragma unroll
        for (int j = 0; j < 3; ++j) acc[i][j] = (f32x4){0.f, 0.f, 0.f, 0.f};

    uint4 ring[3][3][2];
    ushort_t lfr[3][3], rgr[3][3];
    uint4 nx[3][2];
    ushort_t nlf[3], nrg[3];

    auto LOADROW = [&](int YY) {
#pragma unroll
        for (int u = 0; u < 3; ++u) {
            bool ok = ((unsigned)YY < 128u);
            const ushort_t* rp = plane[u] + YY * 128 + pxb[u];
            if (ok) {
                nx[u][0] = *(const uint4*)rp;
                nx[u][1] = *(const uint4*)(rp + 8);
                nlf[u] = (pxb[u] > 0) ? rp[-1] : (ushort_t)0;
                nrg[u] = (pxb[u] + 16 < 128) ? rp[16] : (ushort_t)0;
            } else {
                nx[u][0] = make_uint4(0, 0, 0, 0);
                nx[u][1] = make_uint4(0, 0, 0, 0);
                nlf[u] = 0;
                nrg[u] = 0;
            }
        }
    };
    auto PUT = [&](int rp) {
#pragma unroll
        for (int u = 0; u < 3; ++u) {
            ring[rp][u][0] = nx[u][0];
            ring[rp][u][1] = nx[u][1];
            lfr[rp][u] = nlf[u];
            rgr[rp][u] = nrg[u];
        }
    };

    LOADROW(y0 - 1); PUT(0);
    LOADROW(y0);     PUT(1);
    LOADROW(y0 + 1); PUT(2);

    for (int s = 0; s < 16; ++s) {
        if (s < 15) LOADROW(y0 + s + 2);
#pragma unroll
        for (int u = 0; u < 3; ++u) {
            int id = lane + 64 * u;
            float in[3][18];
#pragma unroll
            for (int r = 0; r < 3; ++r) {
                in[r][0] = bf2f(lfr[r][u]);
                up8(ring[r][u][0], &in[r][1]);
                up8(ring[r][u][1], &in[r][9]);
                in[r][17] = bf2f(rgr[r][u]);
            }
            unsigned pk[8];
#pragma unroll
            for (int j2 = 0; j2 < 8; ++j2) {
                float o0 = 0.f, o1 = 0.f;
#pragma unroll
                for (int ky = 0; ky < 3; ++ky) {
                    o0 = fmaf(wreg[u][ky * 3 + 0], in[ky][2 * j2 + 0], o0);
                    o0 = fmaf(wreg[u][ky * 3 + 1], in[ky][2 * j2 + 1], o0);
                    o0 = fmaf(wreg[u][ky * 3 + 2], in[ky][2 * j2 + 2], o0);
                    o1 = fmaf(wreg[u][ky * 3 + 0], in[ky][2 * j2 + 1], o1);
                    o1 = fmaf(wreg[u][ky * 3 + 1], in[ky][2 * j2 + 2], o1);
                    o1 = fmaf(wreg[u][ky * 3 + 2], in[ky][2 * j2 + 3], o1);
                }
                ssq[u] = fmaf(o0, o0, ssq[u]);
                ssq[u] = fmaf(o1, o1, ssq[u]);
                pk[j2] = (unsigned)f2bf(o0) | ((unsigned)f2bf(o1) << 16);
            }
            uint4* dst = (uint4*)&sCw[(id >> 1) * 40 + ((id & 1) << 4)];
            dst[0] = make_uint4(pk[0], pk[1], pk[2], pk[3]);
            dst[1] = make_uint4(pk[4], pk[5], pk[6], pk[7]);
        }
        {
            bf16x8 af[3], bk[3];
#pragma unroll
            for (int i = 0; i < 3; ++i)
                af[i] = *(const bf16x8*)&sCw[(i * 16 + (lane & 15)) * 40 + (lane >> 4) * 8];
#pragma unroll
            for (int j = 0; j < 3; ++j)
                bk[j] = *(const bf16x8*)&sCw[(48 + j * 16 + (lane & 15)) * 40 + (lane >> 4) * 8];
#pragma unroll
            for (int i = 0; i < 3; ++i)
#pragma unroll
                for (int j = 0; j < 3; ++j)
                    acc[i][j] = __builtin_amdgcn_mfma_f32_16x16x32_bf16(af[i], bk[j],
                                                                        acc[i][j], 0, 0, 0);
        }
        if (s < 15) {
#pragma unroll
            for (int u = 0; u < 3; ++u) {
                ring[0][u][0] = ring[1][u][0]; ring[0][u][1] = ring[1][u][1];
                ring[1][u][0] = ring[2][u][0]; ring[1][u][1] = ring[2][u][1];
                ring[2][u][0] = nx[u][0];      ring[2][u][1] = nx[u][1];
                lfr[0][u] = lfr[1][u]; lfr[1][u] = lfr[2][u]; lfr[2][u] = nlf[u];
                rgr[0][u] = rgr[1][u]; rgr[1][u] = rgr[2][u]; rgr[2][u] = nrg[u];
            }
        }
    }

    __syncthreads();
    const int crow = (lane >> 4) * 4;
    const int dcol = lane & 15;
#pragma unroll
    for (int i = 0; i < 3; ++i)
#pragma unroll
        for (int j = 0; j < 3; ++j)
#pragma unroll
            for (int r = 0; r < 4; ++r)
                sG[(size_t)wave * DH * DH + (i * 16 + crow + r) * DH + j * 16 + dcol] =
                    acc[i][j][r];
    __syncthreads();
    float* g = gpart + (((size_t)(b * NHEADS + h)) * 8 + chunk) * (DH * DH);
    for (int e = t; e < DH * DH; e += 256)
        g[e] = sG[e] + sG[DH * DH + e] + sG[2 * DH * DH + e] + sG[3 * DH * DH + e];

    float* np = normp + ((((size_t)(b * NHEADS + h)) * 8 + chunk) * 4 + wave) * 192;
#pragma unroll
    for (int u = 0; u < 3; ++u) np[lane + 64 * u] = ssq[u];
}

// ---------------------------------------------------------------------------
// k_attn: sum gram+norm partials -> normalize -> softmax -> att fp32
// ---------------------------------------------------------------------------
__global__ __launch_bounds__(256) void k_attn(const float* __restrict__ gpart,
                                              const float* __restrict__ normp,
                                              const float* __restrict__ temperature,
                                              float* __restrict__ att) {
    __shared__ float sA[DH][DH + 1];
    __shared__ float nrm[96];
    const int h = blockIdx.x, b = blockIdx.y;
    const int t = threadIdx.x;
    const size_t bh = b * NHEADS + h;
    if (t < 96) {
        float s = 0.f;
        for (int ck = 0; ck < 8; ++ck)
#pragma unroll
            for (int w = 0; w < 4; ++w) {
                const float* np = normp + ((bh * 8 + ck) * 4 + w) * 192 + t * 2;
                s += np[0] + np[1];
            }
        nrm[t] = fmaxf(sqrtf(s), 1e-12f);
    }
    __syncthreads();
    const float* base = gpart + (bh * 8) * (DH * DH);
    for (int e = t; e < DH * DH; e += 256) {
        float s = 0.f;
#pragma unroll
        for (int c8 = 0; c8 < 8; ++c8) s += base[(size_t)c8 * DH * DH + e];
        int c = e / DH, d = e % DH;
        sA[c][d] = s / (nrm[c] * nrm[48 + d]) * temperature[h];
    }
    __syncthreads();
    if (t < DH) {
        float m = -1e30f;
#pragma unroll
        for (int d = 0; d < DH; ++d) m = fmaxf(m, sA[t][d]);
        float s = 0.f;
        float row[DH];
#pragma unroll
        for (int d = 0; d < DH; ++d) {
            row[d] = expf(sA[t][d] - m);
            s += row[d];
        }
        float inv = 1.f / s;
#pragma unroll
        for (int d = 0; d < DH; ++d) sA[t][d] = row[d] * inv;
    }
    __syncthreads();
    float* ob = att + bh * DH * DH;
    for (int e = t; e < DH * DH; e += 256) ob[e] = sA[e / DH][e % DH];
}

// ---------------------------------------------------------------------------
// k_mw: Mw = proj_w @ blockdiag(att), bf16, written PACKED in fragment order:
// frag (ks,ni16) 1KB block, lane (c*16+r) holds Mw[ni16*16+r][ks*32+c*8..+8].
// ---------------------------------------------------------------------------
__global__ __launch_bounds__(256) void k_mw(const float* __restrict__ att,
                                            const float* __restrict__ proj_w,
                                            ushort_t* __restrict__ Mw) {
    __shared__ float satt[NHEADS][DH][DH];
    __shared__ float sproj[32][CIN];
    const int o0 = blockIdx.x * 32, b = blockIdx.y;
    const int t = threadIdx.x;
    {
        const float4* src = (const float4*)(att + (size_t)b * NHEADS * DH * DH);
        float4* dst = (float4*)&satt[0][0][0];
        for (int e = t; e < NHEADS * DH * DH / 4; e += 256) dst[e] = src[e];
        const float4* ps = (const float4*)(proj_w + (size_t)o0 * CIN);
        float4* pd = (float4*)&sproj[0][0];
        for (int e = t; e < 32 * CIN / 4; e += 256) pd[e] = ps[e];
    }
    __syncthreads();
    ushort_t* ob = Mw + (size_t)b * CIN * CIN;
    for (int e = t; e < 32 * CIN; e += 256) {
        int o = e / CIN, dg = e % CIN;
        int h = dg / DH, d = dg % DH;
        float s = 0.f;
#pragma unroll
        for (int c = 0; c < DH; ++c) s = fmaf(sproj[o][h * DH + c], satt[h][c][d], s);
        int row = o0 + o;
        int ni16 = row >> 4, r = row & 15;
        int ks = dg >> 5, cq = (dg >> 3) & 3, e8 = dg & 7;
        size_t idx = (((size_t)ks * 12 + ni16) * 64 + (cq * 16 + r)) * 8 + e8;
        ob[idx] = f2bf(s);
    }
}

// ---------------------------------------------------------------------------
// k_gemmv: out[o][pix] = sum_ch Mw[o][ch] * dw3x3(v)[ch][pix]
// Conv'd full-K A (128px x 192ch, 48KB) staged ONCE; ONE barrier; then
// 6 K-steps of {2 A ds_reads + 6 direct packed-Mw frag loads + 12 MFMA}.
// ---------------------------------------------------------------------------
__global__ __launch_bounds__(512) void k_gemmv(const ushort_t* __restrict__ pre,
                                               const float* __restrict__ dww,
                                               const ushort_t* __restrict__ Bp,
                                               float* __restrict__ C) {
    __shared__ ushort_t sA[6 * 128 * 32];  // 48 KB
    const int t = threadIdx.x;
    const int lane = t & 63, wave = t >> 6;
    const int wrow = wave >> 1, wcol = wave & 1;
    const int Y = blockIdx.x;
    const int pix0 = Y * 128;
    const int b = blockIdx.z;
    const ushort_t* Bb = Bp + (size_t)b * CIN * CIN;

    const int cc = t >> 4;
    const int jj = t & 15;
    const int x0 = jj * 8;

    // ---- stage conv'd full-K A once ----
#pragma unroll
    for (int c6 = 0; c6 < 6; ++c6) {
        int ch = c6 * 32 + cc;
        const ushort_t* pl = pre + ((size_t)b * C3 + 2 * CIN + ch) * HWPX;
        uint4 m[3];
        ushort_t l16[3], rg16[3];
#pragma unroll
        for (int r = 0; r < 3; ++r) {
            int YY = Y - 1 + r;
            bool ok = ((unsigned)YY < 128u);
            const ushort_t* rp = pl + YY * 128;
            if (ok) {
                m[r] = *(const uint4*)(rp + x0);
                l16[r] = (x0 > 0) ? rp[x0 - 1] : (ushort_t)0;
                rg16[r] = (x0 < 120) ? rp[x0 + 8] : (ushort_t)0;
            } else {
                m[r] = make_uint4(0, 0, 0, 0);
                l16[r] = 0;
                rg16[r] = 0;
            }
        }
        float wv[9];
#pragma unroll
        for (int k = 0; k < 9; ++k) wv[k] = dww[(2 * CIN + ch) * 9 + k];
        float in[3][10];
#pragma unroll
        for (int r = 0; r < 3; ++r) {
            in[r][0] = bf2f(l16[r]);
            up8(m[r], &in[r][1]);
            in[r][9] = bf2f(rg16[r]);
        }
        ushort_t* s = &sA[c6 * 4096];
#pragma unroll
        for (int j = 0; j < 8; ++j) {
            float o = 0.f;
#pragma unroll
            for (int ky = 0; ky < 3; ++ky) {
                o = fmaf(wv[ky * 3 + 0], in[ky][j + 0], o);
                o = fmaf(wv[ky * 3 + 1], in[ky][j + 1], o);
                o = fmaf(wv[ky * 3 + 2], in[ky][j + 2], o);
            }
            int row = jj * 8 + j;
            int slot = ((cc >> 3) + (row >> 1) + (row >> 3)) & 3;
            s[row * 32 + slot * 8 + (cc & 7)] = f2bf(o);
        }
    }
    __syncthreads();  // the ONLY barrier

    const int c = lane >> 4;
    f32x4 acc[2][6];
#pragma unroll
    for (int mi = 0; mi < 2; ++mi)
#pragma unroll
        for (int ni = 0; ni < 6; ++ni) acc[mi][ni] = (f32x4){0.f, 0.f, 0.f, 0.f};

#pragma unroll
    for (int ks = 0; ks < 6; ++ks) {
        const ushort_t* a_ = &sA[ks * 4096];
        bf16x8 af[2], bfr[6];
#pragma unroll
        for (int mi = 0; mi < 2; ++mi) {
            int row = wrow * 32 + mi * 16 + (lane & 15);
            int slot = (c + (row >> 1) + (row >> 3)) & 3;
            af[mi] = *(const bf16x8*)&a_[row * 32 + slot * 8];
        }
#pragma unroll
        for (int ni = 0; ni < 6; ++ni) {
            size_t fidx = (((size_t)ks * 12 + wcol * 6 + ni) * 64 + lane) * 8;
            bfr[ni] = *(const bf16x8*)&Bb[fidx];
        }
#pragma unroll
        for (int mi = 0; mi < 2; ++mi)
#pragma unroll
            for (int ni = 0; ni < 6; ++ni)
                acc[mi][ni] = __builtin_amdgcn_mfma_f32_16x16x32_bf16(
                    af[mi], bfr[ni], acc[mi][ni], 0, 0, 0);
    }

    const int ocol = lane & 15;
    const int prow = (lane >> 4) * 4;
#pragma unroll
    for (int mi = 0; mi < 2; ++mi) {
        int pix = pix0 + wrow * 32 + mi * 16 + prow;
#pragma unroll
        for (int ni = 0; ni < 6; ++ni) {
            int o = wcol * 96 + ni * 16 + ocol;
            f32x4 v = acc[mi][ni];
            float* Cp = C + ((size_t)b * CIN + o) * HWPX + pix;
            *(float4*)Cp = make_float4(v[0], v[1], v[2], v[3]);
        }
    }
}

extern "C" void kernel_launch(void* const* d_in, const int* in_sizes, int n_in,
                              void* d_out, int out_size, void* d_ws, size_t ws_size,
                              hipStream_t stream) {
    const float* x = (const float*)d_in[0];
    const float* qkv_w = (const float*)d_in[1];
    const float* dw_w = (const float*)d_in[2];
    const float* proj_w = (const float*)d_in[3];
    const float* temperature = (const float*)d_in[4];
    float* out = (float*)d_out;

    char* ws = (char*)d_ws;
    ushort_t* pre = (ushort_t*)ws;
    float* normp = (float*)(ws + 150994944);
    float* gpart = (float*)(ws + 151781376);
    ushort_t* Mw = (ushort_t*)(ws + 154140672);
    float* attb = (float*)(ws + 154730496);
    ushort_t* wq = (ushort_t*)(ws + 155025408);

    k_cvtw<<<dim3(108), 256, 0, stream>>>(qkv_w, wq);
    k_gemm<<<dim3(128, 1, 8), 512, 0, stream>>>(x, wq, pre);
    k_gramdw<<<dim3(8, NHEADS, 8), 256, 0, stream>>>(pre, dw_w, gpart, normp);
    k_attn<<<dim3(NHEADS, 8), 256, 0, stream>>>(gpart, normp, temperature, attb);
    k_mw<<<dim3(6, 8), 256, 0, stream>>>(attb, proj_w, Mw);
    k_gemmv<<<dim3(128, 1, 8), 512, 0, stream>>>(pre, dw_w, Mw, out);
}